// Round 1
// baseline (512.726 us; speedup 1.0000x reference)
//
#include <hip/hip_runtime.h>
#include <math.h>

#define N_NODES 50000
#define N_EDGES 800000
#define ETOT    (N_EDGES + N_NODES)   // 850000, with self loops

typedef short bf16x8 __attribute__((ext_vector_type(8)));
typedef float f32x4  __attribute__((ext_vector_type(4)));
typedef float f32x2  __attribute__((ext_vector_type(2)));

__device__ __forceinline__ float b2f(unsigned int u16) {   // low 16 bits hold bf16
    return __uint_as_float(u16 << 16);
}
__device__ __forceinline__ unsigned short f2b(float f) {   // RNE
    unsigned int u = __float_as_uint(f);
    u += 0x7fffu + ((u >> 16) & 1u);
    return (unsigned short)(u >> 16);
}

// ---------------------------------------------------------------------------
// Prep: zero deg+flag, cast W1/W2/W3 fp32->bf16, cast x fp32->bf16.
// Grid 3125x256 = 800000 threads (x cast: 8 floats/thread).
// ---------------------------------------------------------------------------
__global__ __launch_bounds__(256) void k_prep(const float* __restrict__ x,
                                              const float* __restrict__ w1,
                                              const float* __restrict__ w2,
                                              const float* __restrict__ w3,
                                              unsigned short* __restrict__ xb,
                                              unsigned short* __restrict__ o1,
                                              unsigned short* __restrict__ o2,
                                              unsigned short* __restrict__ o3,
                                              int* __restrict__ deg,
                                              int* __restrict__ flag) {
    int i = blockIdx.x * 256 + threadIdx.x;
    if (i < N_NODES) deg[i] = 0;
    if (i == 0) *flag = 0;
    if (i < 512 * 128 / 4) {
        float4 v = ((const float4*)w1)[i];
        ushort2* o = (ushort2*)(o1 + i * 4);
        o[0] = make_ushort2(f2b(v.x), f2b(v.y));
        o[1] = make_ushort2(f2b(v.z), f2b(v.w));
    }
    if (i < 64 * 512 / 4) {
        float4 v = ((const float4*)w2)[i];
        ushort2* o = (ushort2*)(o2 + i * 4);
        o[0] = make_ushort2(f2b(v.x), f2b(v.y));
        o[1] = make_ushort2(f2b(v.z), f2b(v.w));
    }
    if (i < 64 * 64 / 4) {
        float4 v = ((const float4*)w3)[i];
        ushort2* o = (ushort2*)(o3 + i * 4);
        o[0] = make_ushort2(f2b(v.x), f2b(v.y));
        o[1] = make_ushort2(f2b(v.z), f2b(v.w));
    }
    if (i < N_NODES * 128 / 8) {
        const float4* xp = (const float4*)x + (size_t)i * 2;
        float4 v0 = xp[0], v1 = xp[1];
        unsigned int u0 = (unsigned int)f2b(v0.x) | ((unsigned int)f2b(v0.y) << 16);
        unsigned int u1 = (unsigned int)f2b(v0.z) | ((unsigned int)f2b(v0.w) << 16);
        unsigned int u2 = (unsigned int)f2b(v1.x) | ((unsigned int)f2b(v1.y) << 16);
        unsigned int u3 = (unsigned int)f2b(v1.z) | ((unsigned int)f2b(v1.w) << 16);
        *(uint4*)(xb + (size_t)i * 8) = make_uint4(u0, u1, u2, u3);
    }
}

// ---------------------------------------------------------------------------
// Edge-index dtype detection (reference int64 vs harness int32).
// ---------------------------------------------------------------------------
__global__ void k_detect(const int* __restrict__ idx, int* __restrict__ flag) {
    int i = blockIdx.x * blockDim.x + threadIdx.x;   // 8192 threads
    int v = idx[2 * i + 1];
    unsigned long long any = __ballot(v != 0);
    if ((threadIdx.x & 63) == 0 && any) atomicOr(flag, 1);   // 1 => int32 data
}

__device__ __forceinline__ int edge_src(const int* idx, int e, int is32) {
    return is32 ? idx[e] : idx[2 * e];
}
__device__ __forceinline__ int edge_dst(const int* idx, int e, int is32) {
    return is32 ? idx[N_EDGES + e] : idx[2 * (N_EDGES + e)];
}

// ---------------------------------------------------------------------------
// CSR build: degree -> 3-kernel scan -> scatter
// ---------------------------------------------------------------------------
__global__ void k_degree(const int* __restrict__ idx, const int* __restrict__ flag,
                         int* __restrict__ deg) {
    int e = blockIdx.x * blockDim.x + threadIdx.x;
    if (e >= ETOT) return;
    int is32 = *flag;
    int d = (e < N_EDGES) ? edge_dst(idx, e, is32) : (e - N_EDGES);
    atomicAdd(&deg[d], 1);
}

__global__ __launch_bounds__(256) void k_scan1(const int* __restrict__ deg,
                                               int* __restrict__ rowptr,
                                               int* __restrict__ bsum) {
    __shared__ int sd[256];
    int t = threadIdx.x;
    int i = blockIdx.x * 256 + t;
    int v = (i < N_NODES) ? deg[i] : 0;
    sd[t] = v;
    __syncthreads();
#pragma unroll
    for (int off = 1; off < 256; off <<= 1) {
        int a = (t >= off) ? sd[t - off] : 0;
        __syncthreads();
        sd[t] += a;
        __syncthreads();
    }
    if (i < N_NODES) rowptr[i] = sd[t] - v;    // block-local exclusive
    if (t == 255) bsum[blockIdx.x] = sd[255];
}

__global__ __launch_bounds__(256) void k_scan2(int* __restrict__ bsum,
                                               int* __restrict__ boff,
                                               int* __restrict__ rowptr,
                                               int nb) {
    __shared__ int sd[256];
    int t = threadIdx.x;
    int v = (t < nb) ? bsum[t] : 0;
    sd[t] = v;
    __syncthreads();
#pragma unroll
    for (int off = 1; off < 256; off <<= 1) {
        int a = (t >= off) ? sd[t - off] : 0;
        __syncthreads();
        sd[t] += a;
        __syncthreads();
    }
    boff[t] = sd[t] - v;                        // exclusive
    if (t == 255) rowptr[N_NODES] = sd[255];
}

__global__ __launch_bounds__(256) void k_scan3(int* __restrict__ rowptr,
                                               const int* __restrict__ boff,
                                               int* __restrict__ cursor) {
    int i = blockIdx.x * 256 + threadIdx.x;
    if (i >= N_NODES) return;
    int r = rowptr[i] + boff[blockIdx.x];
    rowptr[i] = r;
    cursor[i] = r;
}

__global__ void k_scatter(const int* __restrict__ idx, const int* __restrict__ flag,
                          int* __restrict__ cursor, int* __restrict__ col) {
    int e = blockIdx.x * blockDim.x + threadIdx.x;
    if (e >= ETOT) return;
    int is32 = *flag;
    int s, d;
    if (e < N_EDGES) { s = edge_src(idx, e, is32); d = edge_dst(idx, e, is32); }
    else             { s = d = e - N_EDGES; }
    int pos = atomicAdd(&cursor[d], 1);
    col[pos] = s;
}

// ---------------------------------------------------------------------------
// bf16 MFMA GEMM: C[M,Nout] = A[M,K] @ W[Nout,K]^T.
// 64x64 block tile, 256 threads = 4 waves; wave w owns cols [16w,16w+16);
// 4 row-tiles of 16 per wave via mfma_f32_16x16x32_bf16. K % 32 == 0.
// Epilogue computes attention coefficients from fp32 acc (col block = head).
// ---------------------------------------------------------------------------
template<int AFP32>
__global__ __launch_bounds__(256) void k_gemm(const float* __restrict__ Af,
                                              const unsigned short* __restrict__ Ab,
                                              const unsigned short* __restrict__ W,
                                              unsigned short* __restrict__ C,
                                              const float* __restrict__ a_src,
                                              const float* __restrict__ a_dst,
                                              float* __restrict__ asb,
                                              float* __restrict__ adb,
                                              int M, int K, int Nout, int Hstr) {
    __shared__ unsigned short As[64 * 40];   // row stride 40 shorts (80 B)
    __shared__ unsigned short Bs[64 * 40];
    __shared__ float red_s[4][64];
    __shared__ float red_d[4][64];
    int t = threadIdx.x;
    int w = t >> 6, l = t & 63;
    int quad = l >> 4, lm = l & 15;
    int m0 = blockIdx.y * 64, n0 = blockIdx.x * 64;
    int hd = blockIdx.x;
    int lr = t >> 2;            // staging row 0..63
    int lc = (t & 3) * 8;       // staging col offset 0/8/16/24

    f32x4 acc[4];
#pragma unroll
    for (int r = 0; r < 4; ++r) acc[r] = (f32x4){0.f, 0.f, 0.f, 0.f};

    for (int k0 = 0; k0 < K; k0 += 32) {
        int m = m0 + lr;
        if (AFP32) {
            float4 a0 = {0.f,0.f,0.f,0.f}, a1 = {0.f,0.f,0.f,0.f};
            if (m < M) {
                const float4* ap = (const float4*)(Af + (size_t)m * K + k0 + lc);
                a0 = ap[0]; a1 = ap[1];
            }
            unsigned int u0 = (unsigned int)f2b(a0.x) | ((unsigned int)f2b(a0.y) << 16);
            unsigned int u1 = (unsigned int)f2b(a0.z) | ((unsigned int)f2b(a0.w) << 16);
            unsigned int u2 = (unsigned int)f2b(a1.x) | ((unsigned int)f2b(a1.y) << 16);
            unsigned int u3 = (unsigned int)f2b(a1.z) | ((unsigned int)f2b(a1.w) << 16);
            *(uint4*)&As[lr * 40 + lc] = make_uint4(u0, u1, u2, u3);
        } else {
            uint4 av = make_uint4(0, 0, 0, 0);
            if (m < M) av = *(const uint4*)(Ab + (size_t)m * K + k0 + lc);
            *(uint4*)&As[lr * 40 + lc] = av;
        }
        uint4 bv = *(const uint4*)(W + (size_t)(n0 + lr) * K + k0 + lc);
        *(uint4*)&Bs[lr * 40 + lc] = bv;
        __syncthreads();

        bf16x8 bfrag = *(const bf16x8*)&Bs[(w * 16 + lm) * 40 + quad * 8];
#pragma unroll
        for (int r = 0; r < 4; ++r) {
            bf16x8 afrag = *(const bf16x8*)&As[(r * 16 + lm) * 40 + quad * 8];
            acc[r] = __builtin_amdgcn_mfma_f32_16x16x32_bf16(afrag, bfrag, acc[r], 0, 0, 0);
        }
        __syncthreads();
    }

    // C store (bf16)
#pragma unroll
    for (int r = 0; r < 4; ++r)
#pragma unroll
        for (int g = 0; g < 4; ++g) {
            int m = m0 + r * 16 + quad * 4 + g;
            if (m < M) C[(size_t)m * Nout + n0 + w * 16 + lm] = f2b(acc[r][g]);
        }

    // Attention-coefficient epilogue (fp32 accumulators)
    float as = a_src[hd * 64 + w * 16 + lm];
    float ad = a_dst[hd * 64 + w * 16 + lm];
#pragma unroll
    for (int r = 0; r < 4; ++r) {
#pragma unroll
        for (int g = 0; g < 4; ++g) {
            float vs = acc[r][g] * as;
            float vd = acc[r][g] * ad;
#pragma unroll
            for (int off = 1; off < 16; off <<= 1) {
                vs += __shfl_xor(vs, off);
                vd += __shfl_xor(vd, off);
            }
            if (lm == 0) {
                red_s[w][r * 16 + quad * 4 + g] = vs;
                red_d[w][r * 16 + quad * 4 + g] = vd;
            }
        }
    }
    __syncthreads();
    if (t < 64) {
        float vs = red_s[0][t] + red_s[1][t] + red_s[2][t] + red_s[3][t];
        float vd = red_d[0][t] + red_d[1][t] + red_d[2][t] + red_d[3][t];
        int m = m0 + t;
        if (m < M) {
            asb[(size_t)m * Hstr + hd] = vs;
            adb[(size_t)m * Hstr + hd] = vd;
        }
    }
}

// ---------------------------------------------------------------------------
// Fused segment-softmax + aggregation, H=8, C=64 (layer 1), bf16 h.
// Single pass, no max subtraction (|e| <= ~2 analytically).
// v2: u32 offset math (saddr-form gathers), int4 col loads with next-iter
// prefetch, packed v_pk_fma_f32 accumulation.
// ---------------------------------------------------------------------------
__device__ __forceinline__ void agg8_acc(float t, float adn, uint4 hv,
                                         float& ssum, f32x2* o2) {
    float e = t + adn;
    e = fmaxf(e, 0.2f * e);                    // leaky_relu, slope 0.2
    float ex = __expf(e);
    ssum += ex;
    f32x2 ex2 = {ex, ex};
    f32x2 f;
    f.x = __uint_as_float(hv.x << 16); f.y = __uint_as_float(hv.x & 0xffff0000u);
    asm("v_pk_fma_f32 %0, %1, %2, %0" : "+v"(o2[0]) : "v"(f), "v"(ex2));
    f.x = __uint_as_float(hv.y << 16); f.y = __uint_as_float(hv.y & 0xffff0000u);
    asm("v_pk_fma_f32 %0, %1, %2, %0" : "+v"(o2[1]) : "v"(f), "v"(ex2));
    f.x = __uint_as_float(hv.z << 16); f.y = __uint_as_float(hv.z & 0xffff0000u);
    asm("v_pk_fma_f32 %0, %1, %2, %0" : "+v"(o2[2]) : "v"(f), "v"(ex2));
    f.x = __uint_as_float(hv.w << 16); f.y = __uint_as_float(hv.w & 0xffff0000u);
    asm("v_pk_fma_f32 %0, %1, %2, %0" : "+v"(o2[3]) : "v"(f), "v"(ex2));
}

__global__ __launch_bounds__(256) void k_agg8(const unsigned short* __restrict__ h, // [N,512]
                                              const float* __restrict__ asrc,       // [N,8]
                                              const float* __restrict__ adst,       // [N,8]
                                              const int* __restrict__ rowptr,
                                              const int* __restrict__ col,
                                              const float* __restrict__ bias,       // [512]
                                              unsigned short* __restrict__ out) {   // [N,512]
    int n = blockIdx.x * 4 + (threadIdx.x >> 6);
    if (n >= N_NODES) return;
    int l = threadIdx.x & 63;
    int j = l >> 3;
    int lbase = l << 3;
    int start = rowptr[n], end = rowptr[n + 1];
    float adn = adst[(n << 3) + j];

    float ssum = 0.f;
    f32x2 o2[4];
#pragma unroll
    for (int i = 0; i < 4; ++i) o2[i] = (f32x2){0.f, 0.f};

    int k = start;
    int kA = (start + 3) & ~3;                 // align to int4 col loads
    if (kA > end) kA = end;
    for (; k < kA; ++k) {
        int s = col[k];
        float t = asrc[((unsigned)s << 3) + (unsigned)j];
        uint4 hv = *(const uint4*)(h + ((unsigned)s << 9) + (unsigned)lbase);
        agg8_acc(t, adn, hv, ssum, o2);
    }
    int kEnd4 = kA + ((end - kA) & ~3);
    if (k < kEnd4) {
        int4 cN = *(const int4*)(col + k);
        for (; k < kEnd4; k += 4) {
            int4 c = cN;
            if (k + 8 <= kEnd4) cN = *(const int4*)(col + k + 4);
            float t0 = asrc[((unsigned)c.x << 3) + (unsigned)j];
            float t1 = asrc[((unsigned)c.y << 3) + (unsigned)j];
            float t2 = asrc[((unsigned)c.z << 3) + (unsigned)j];
            float t3 = asrc[((unsigned)c.w << 3) + (unsigned)j];
            uint4 hv0 = *(const uint4*)(h + ((unsigned)c.x << 9) + (unsigned)lbase);
            uint4 hv1 = *(const uint4*)(h + ((unsigned)c.y << 9) + (unsigned)lbase);
            uint4 hv2 = *(const uint4*)(h + ((unsigned)c.z << 9) + (unsigned)lbase);
            uint4 hv3 = *(const uint4*)(h + ((unsigned)c.w << 9) + (unsigned)lbase);
            agg8_acc(t0, adn, hv0, ssum, o2);
            agg8_acc(t1, adn, hv1, ssum, o2);
            agg8_acc(t2, adn, hv2, ssum, o2);
            agg8_acc(t3, adn, hv3, ssum, o2);
        }
    }
    for (; k < end; ++k) {
        int s = col[k];
        float t = asrc[((unsigned)s << 3) + (unsigned)j];
        uint4 hv = *(const uint4*)(h + ((unsigned)s << 9) + (unsigned)lbase);
        agg8_acc(t, adn, hv, ssum, o2);
    }

    float inv = 1.f / (ssum + 1e-16f);
    unsigned int p[4];
#pragma unroll
    for (int i = 0; i < 4; ++i) {
        float v0 = o2[i].x * inv + bias[lbase + 2 * i];
        float v1 = o2[i].y * inv + bias[lbase + 2 * i + 1];
        v0 = (v0 > 0.f) ? v0 : expm1f(v0);
        v1 = (v1 > 0.f) ? v1 : expm1f(v1);
        p[i] = (unsigned int)f2b(v0) | ((unsigned int)f2b(v1) << 16);
    }
    *(uint4*)(out + (size_t)n * 512 + lbase) = make_uint4(p[0], p[1], p[2], p[3]);
}

// ---------------------------------------------------------------------------
// Fused segment-softmax + aggregation, H=1, C=64 (layers 2,3), bf16 h.
// v2: u32 offsets + int4 col loads with prefetch.
// ---------------------------------------------------------------------------
__global__ __launch_bounds__(256) void k_agg1(const unsigned short* __restrict__ h, // [N,64]
                                              const float* __restrict__ asrc,       // [N]
                                              const float* __restrict__ adst,       // [N]
                                              const int* __restrict__ rowptr,
                                              const int* __restrict__ col,
                                              const float* __restrict__ bias,       // [64]
                                              unsigned short* __restrict__ out) {   // [N,64]
    int n = blockIdx.x * 4 + (threadIdx.x >> 6);
    if (n >= N_NODES) return;
    int l = threadIdx.x & 63;
    int start = rowptr[n], end = rowptr[n + 1];
    float adn = adst[n];

    float ssum = 0.f, o = 0.f;
    int k = start;
    int kA = (start + 3) & ~3;
    if (kA > end) kA = end;
    for (; k < kA; ++k) {
        int s = col[k];
        float t = asrc[s];
        float hf = b2f(h[((unsigned)s << 6) + (unsigned)l]);
        float e = t + adn; e = fmaxf(e, 0.2f * e);
        float ex = __expf(e);
        ssum += ex; o += ex * hf;
    }
    int kEnd4 = kA + ((end - kA) & ~3);
    if (k < kEnd4) {
        int4 cN = *(const int4*)(col + k);
        for (; k < kEnd4; k += 4) {
            int4 c = cN;
            if (k + 8 <= kEnd4) cN = *(const int4*)(col + k + 4);
            float t0 = asrc[c.x], t1 = asrc[c.y], t2 = asrc[c.z], t3 = asrc[c.w];
            unsigned short q0 = h[((unsigned)c.x << 6) + (unsigned)l];
            unsigned short q1 = h[((unsigned)c.y << 6) + (unsigned)l];
            unsigned short q2 = h[((unsigned)c.z << 6) + (unsigned)l];
            unsigned short q3 = h[((unsigned)c.w << 6) + (unsigned)l];
            float e0 = t0 + adn; e0 = fmaxf(e0, 0.2f * e0);
            float ex0 = __expf(e0); ssum += ex0; o += ex0 * b2f(q0);
            float e1 = t1 + adn; e1 = fmaxf(e1, 0.2f * e1);
            float ex1 = __expf(e1); ssum += ex1; o += ex1 * b2f(q1);
            float e2 = t2 + adn; e2 = fmaxf(e2, 0.2f * e2);
            float ex2 = __expf(e2); ssum += ex2; o += ex2 * b2f(q2);
            float e3 = t3 + adn; e3 = fmaxf(e3, 0.2f * e3);
            float ex3 = __expf(e3); ssum += ex3; o += ex3 * b2f(q3);
        }
    }
    for (; k < end; ++k) {
        int s = col[k];
        float t = asrc[s];
        float hf = b2f(h[((unsigned)s << 6) + (unsigned)l]);
        float e = t + adn; e = fmaxf(e, 0.2f * e);
        float ex = __expf(e);
        ssum += ex; o += ex * hf;
    }
    float v = o / (ssum + 1e-16f) + bias[l];
    v = (v > 0.f) ? v : expm1f(v);   // ELU
    out[(size_t)n * 64 + l] = f2b(v);
}

// ---------------------------------------------------------------------------
// Classifier: out[N,10] = h[N,64](bf16) @ Wc[10,64]^T + bc, fp32 out.
// ---------------------------------------------------------------------------
__global__ __launch_bounds__(256) void k_classifier(const unsigned short* __restrict__ h,
                                                    const float* __restrict__ Wc,
                                                    const float* __restrict__ bc,
                                                    float* __restrict__ out) {
    __shared__ float sW[640];
    for (int i = threadIdx.x; i < 640; i += blockDim.x) sW[i] = Wc[i];
    __syncthreads();
    int idx = blockIdx.x * blockDim.x + threadIdx.x;
    if (idx >= N_NODES * 10) return;
    int n = idx / 10, d = idx - n * 10;
    const unsigned short* hr = h + (size_t)n * 64;
    const float* wr = sW + d * 64;
    float acc = 0.f;
#pragma unroll
    for (int c = 0; c < 64; ++c) acc += b2f(hr[c]) * wr[c];
    out[idx] = acc + bc[d];
}

// ---------------------------------------------------------------------------
extern "C" void kernel_launch(void* const* d_in, const int* in_sizes, int n_in,
                              void* d_out, int out_size, void* d_ws, size_t ws_size,
                              hipStream_t stream) {
    const float* x    = (const float*)d_in[0];
    const int*   eidx = (const int*)  d_in[1];
    const float* W1   = (const float*)d_in[2];
    const float* a1s  = (const float*)d_in[3];
    const float* a1d  = (const float*)d_in[4];
    const float* b1   = (const float*)d_in[5];
    const float* W2   = (const float*)d_in[6];
    const float* a2s  = (const float*)d_in[7];
    const float* a2d  = (const float*)d_in[8];
    const float* b2   = (const float*)d_in[9];
    const float* W3   = (const float*)d_in[10];
    const float* a3s  = (const float*)d_in[11];
    const float* a3d  = (const float*)d_in[12];
    const float* b3   = (const float*)d_in[13];
    const float* Wc   = (const float*)d_in[14];
    const float* bc   = (const float*)d_in[15];
    float* out = (float*)d_out;

    // Workspace layout: fp32 first (16B alignment), then bf16, then ints
    float* asbuf = (float*)d_ws;                              // N*8
    float* adbuf = asbuf + (size_t)N_NODES * 8;               // N*8
    unsigned short* h1  = (unsigned short*)(adbuf + (size_t)N_NODES * 8); // N*512
    unsigned short* x2  = h1  + (size_t)N_NODES * 512;        // N*512
    unsigned short* h2  = x2  + (size_t)N_NODES * 512;        // N*64
    unsigned short* x3  = h2  + (size_t)N_NODES * 64;         // N*64
    unsigned short* h3  = x3  + (size_t)N_NODES * 64;         // N*64
    unsigned short* x4  = h3  + (size_t)N_NODES * 64;         // N*64
    unsigned short* xb  = x4  + (size_t)N_NODES * 64;         // N*128 (bf16 x)
    unsigned short* W1b = xb  + (size_t)N_NODES * 128;        // 512*128
    unsigned short* W2b = W1b + 512 * 128;                    // 64*512
    unsigned short* W3b = W2b + 64 * 512;                     // 64*64
    int* ibase  = (int*)(W3b + 64 * 64);
    int* deg    = ibase;                                      // N   (zeroed in k_prep)
    int* flag   = deg + N_NODES;                              // 1   (zeroed in k_prep)
    int* rowptr = flag + 1;                                   // N+1
    int* cursor = rowptr + N_NODES + 1;                       // N
    int* bsum   = cursor + N_NODES;                           // 256
    int* boff   = bsum + 256;                                 // 256
    int* col    = boff + 256;                                 // ETOT

    dim3 blk(256);
    const int SCAN_BLOCKS = (N_NODES + 255) / 256;            // 196
    const int PREP_BLOCKS = (N_NODES * 128 / 8 + 255) / 256;  // 3125

    // Prep (zero deg/flag + weight & x casts), then CSR build
    k_prep<<<PREP_BLOCKS, blk, 0, stream>>>(x, W1, W2, W3, xb, W1b, W2b, W3b, deg, flag);
    k_detect<<<32, blk, 0, stream>>>(eidx, flag);
    k_degree<<<(ETOT + 255) / 256, blk, 0, stream>>>(eidx, flag, deg);
    k_scan1<<<SCAN_BLOCKS, blk, 0, stream>>>(deg, rowptr, bsum);
    k_scan2<<<1, blk, 0, stream>>>(bsum, boff, rowptr, SCAN_BLOCKS);
    k_scan3<<<SCAN_BLOCKS, blk, 0, stream>>>(rowptr, boff, cursor);
    k_scatter<<<(ETOT + 255) / 256, blk, 0, stream>>>(eidx, flag, cursor, col);

    int mblocks = (N_NODES + 63) / 64;   // 782
    int nblocks = N_NODES / 4;           // 12500 (exact)

    // Layer 1: xb[N,128] bf16 -> h1[N,512] (+ attn coefs); agg -> x2
    k_gemm<0><<<dim3(8, mblocks), blk, 0, stream>>>((const float*)0, xb, W1b, h1,
                                                    a1s, a1d, asbuf, adbuf,
                                                    N_NODES, 128, 512, 8);
    k_agg8<<<nblocks, blk, 0, stream>>>(h1, asbuf, adbuf, rowptr, col, b1, x2);

    // Layer 2: x2[N,512] -> h2[N,64] (+ attn coefs); agg -> x3
    k_gemm<0><<<dim3(1, mblocks), blk, 0, stream>>>((const float*)0, x2, W2b, h2,
                                                    a2s, a2d, asbuf, adbuf,
                                                    N_NODES, 512, 64, 1);
    k_agg1<<<nblocks, blk, 0, stream>>>(h2, asbuf, adbuf, rowptr, col, b2, x3);

    // Layer 3: x3[N,64] -> h3[N,64] (+ attn coefs); agg -> x4
    k_gemm<0><<<dim3(1, mblocks), blk, 0, stream>>>((const float*)0, x3, W3b, h3,
                                                    a3s, a3d, asbuf, adbuf,
                                                    N_NODES, 64, 64, 1);
    k_agg1<<<nblocks, blk, 0, stream>>>(h3, asbuf, adbuf, rowptr, col, b3, x4);

    // Classifier
    k_classifier<<<(N_NODES * 10 + 255) / 256, blk, 0, stream>>>(x4, Wc, bc, out);
}

// Round 2
// 503.229 us; speedup vs baseline: 1.0189x; 1.0189x over previous
//
#include <hip/hip_runtime.h>
#include <math.h>

#define N_NODES 50000
#define N_EDGES 800000
#define ETOT    (N_EDGES + N_NODES)   // 850000, with self loops
// col array: padded rows (each row padded to multiple of 4) + 16-int tail
#define COL_CAP (ETOT + 3 * N_NODES + 16)

typedef short bf16x8 __attribute__((ext_vector_type(8)));
typedef float f32x4  __attribute__((ext_vector_type(4)));
typedef float f32x2  __attribute__((ext_vector_type(2)));

__device__ __forceinline__ float b2f(unsigned int u16) {   // low 16 bits hold bf16
    return __uint_as_float(u16 << 16);
}
__device__ __forceinline__ unsigned short f2b(float f) {   // RNE
    unsigned int u = __float_as_uint(f);
    u += 0x7fffu + ((u >> 16) & 1u);
    return (unsigned short)(u >> 16);
}

// ---------------------------------------------------------------------------
// Prep: zero deg+flag, cast W1/W2/W3 fp32->bf16, cast x fp32->bf16.
// ---------------------------------------------------------------------------
__global__ __launch_bounds__(256) void k_prep(const float* __restrict__ x,
                                              const float* __restrict__ w1,
                                              const float* __restrict__ w2,
                                              const float* __restrict__ w3,
                                              unsigned short* __restrict__ xb,
                                              unsigned short* __restrict__ o1,
                                              unsigned short* __restrict__ o2,
                                              unsigned short* __restrict__ o3,
                                              int* __restrict__ deg,
                                              int* __restrict__ flag) {
    int i = blockIdx.x * 256 + threadIdx.x;
    if (i < N_NODES) deg[i] = 0;
    if (i == 0) *flag = 0;
    if (i < 512 * 128 / 4) {
        float4 v = ((const float4*)w1)[i];
        ushort2* o = (ushort2*)(o1 + i * 4);
        o[0] = make_ushort2(f2b(v.x), f2b(v.y));
        o[1] = make_ushort2(f2b(v.z), f2b(v.w));
    }
    if (i < 64 * 512 / 4) {
        float4 v = ((const float4*)w2)[i];
        ushort2* o = (ushort2*)(o2 + i * 4);
        o[0] = make_ushort2(f2b(v.x), f2b(v.y));
        o[1] = make_ushort2(f2b(v.z), f2b(v.w));
    }
    if (i < 64 * 64 / 4) {
        float4 v = ((const float4*)w3)[i];
        ushort2* o = (ushort2*)(o3 + i * 4);
        o[0] = make_ushort2(f2b(v.x), f2b(v.y));
        o[1] = make_ushort2(f2b(v.z), f2b(v.w));
    }
    if (i < N_NODES * 128 / 8) {
        const float4* xp = (const float4*)x + (size_t)i * 2;
        float4 v0 = xp[0], v1 = xp[1];
        unsigned int u0 = (unsigned int)f2b(v0.x) | ((unsigned int)f2b(v0.y) << 16);
        unsigned int u1 = (unsigned int)f2b(v0.z) | ((unsigned int)f2b(v0.w) << 16);
        unsigned int u2 = (unsigned int)f2b(v1.x) | ((unsigned int)f2b(v1.y) << 16);
        unsigned int u3 = (unsigned int)f2b(v1.z) | ((unsigned int)f2b(v1.w) << 16);
        *(uint4*)(xb + (size_t)i * 8) = make_uint4(u0, u1, u2, u3);
    }
}

// ---------------------------------------------------------------------------
// Edge-index dtype detection (reference int64 vs harness int32).
// ---------------------------------------------------------------------------
__global__ void k_detect(const int* __restrict__ idx, int* __restrict__ flag) {
    int i = blockIdx.x * blockDim.x + threadIdx.x;   // 8192 threads
    int v = idx[2 * i + 1];
    unsigned long long any = __ballot(v != 0);
    if ((threadIdx.x & 63) == 0 && any) atomicOr(flag, 1);   // 1 => int32 data
}

__device__ __forceinline__ int edge_src(const int* idx, int e, int is32) {
    return is32 ? idx[e] : idx[2 * e];
}
__device__ __forceinline__ int edge_dst(const int* idx, int e, int is32) {
    return is32 ? idx[N_EDGES + e] : idx[2 * (N_EDGES + e)];
}

// ---------------------------------------------------------------------------
// CSR build: degree -> 3-kernel scan (PADDED row starts) -> scatter
// Rows are padded to a multiple of 4 entries; pad slots hold col=0 and are
// predicated out of the aggregation (exp weight forced to 0).
// ---------------------------------------------------------------------------
__global__ void k_degree(const int* __restrict__ idx, const int* __restrict__ flag,
                         int* __restrict__ deg) {
    int e = blockIdx.x * blockDim.x + threadIdx.x;
    if (e >= ETOT) return;
    int is32 = *flag;
    int d = (e < N_EDGES) ? edge_dst(idx, e, is32) : (e - N_EDGES);
    atomicAdd(&deg[d], 1);
}

__global__ __launch_bounds__(256) void k_scan1(const int* __restrict__ deg,
                                               int* __restrict__ rowptr,
                                               int* __restrict__ bsum) {
    __shared__ int sd[256];
    int t = threadIdx.x;
    int i = blockIdx.x * 256 + t;
    int v = (i < N_NODES) ? ((deg[i] + 3) & ~3) : 0;   // padded degree
    sd[t] = v;
    __syncthreads();
#pragma unroll
    for (int off = 1; off < 256; off <<= 1) {
        int a = (t >= off) ? sd[t - off] : 0;
        __syncthreads();
        sd[t] += a;
        __syncthreads();
    }
    if (i < N_NODES) rowptr[i] = sd[t] - v;    // block-local exclusive (padded)
    if (t == 255) bsum[blockIdx.x] = sd[255];
}

__global__ __launch_bounds__(256) void k_scan2(int* __restrict__ bsum,
                                               int* __restrict__ boff,
                                               int* __restrict__ rowptr,
                                               int nb) {
    __shared__ int sd[256];
    int t = threadIdx.x;
    int v = (t < nb) ? bsum[t] : 0;
    sd[t] = v;
    __syncthreads();
#pragma unroll
    for (int off = 1; off < 256; off <<= 1) {
        int a = (t >= off) ? sd[t - off] : 0;
        __syncthreads();
        sd[t] += a;
        __syncthreads();
    }
    boff[t] = sd[t] - v;                        // exclusive
    if (t == 255) rowptr[N_NODES] = sd[255];    // total padded length
}

__global__ __launch_bounds__(256) void k_scan3(int* __restrict__ rowptr,
                                               const int* __restrict__ boff,
                                               const int* __restrict__ deg,
                                               int* __restrict__ cursor,
                                               int* __restrict__ col) {
    int i = blockIdx.x * 256 + threadIdx.x;
    if (i == 0) {                                // zero 16-int tail pad
        int tot = rowptr[N_NODES];
        for (int q = 0; q < 16; ++q) col[tot + q] = 0;
    }
    if (i >= N_NODES) return;
    int r = rowptr[i] + boff[blockIdx.x];
    rowptr[i] = r;
    cursor[i] = r;
    int d = deg[i];
    int pd = (d + 3) & ~3;
    for (int p = r + d; p < r + pd; ++p) col[p] = 0;   // zero row pads
}

__global__ void k_scatter(const int* __restrict__ idx, const int* __restrict__ flag,
                          int* __restrict__ cursor, int* __restrict__ col) {
    int e = blockIdx.x * blockDim.x + threadIdx.x;
    if (e >= ETOT) return;
    int is32 = *flag;
    int s, d;
    if (e < N_EDGES) { s = edge_src(idx, e, is32); d = edge_dst(idx, e, is32); }
    else             { s = d = e - N_EDGES; }
    int pos = atomicAdd(&cursor[d], 1);
    col[pos] = s;
}

// ---------------------------------------------------------------------------
// bf16 MFMA GEMM: C[M,Nout] = A[M,K] @ W[Nout,K]^T.
// 64x64 block tile, 256 threads = 4 waves; wave w owns cols [16w,16w+16);
// 4 row-tiles of 16 per wave via mfma_f32_16x16x32_bf16. K % 32 == 0.
// Epilogue computes attention coefficients from fp32 acc (col block = head).
// ---------------------------------------------------------------------------
template<int AFP32>
__global__ __launch_bounds__(256) void k_gemm(const float* __restrict__ Af,
                                              const unsigned short* __restrict__ Ab,
                                              const unsigned short* __restrict__ W,
                                              unsigned short* __restrict__ C,
                                              const float* __restrict__ a_src,
                                              const float* __restrict__ a_dst,
                                              float* __restrict__ asb,
                                              float* __restrict__ adb,
                                              int M, int K, int Nout, int Hstr) {
    __shared__ unsigned short As[64 * 40];   // row stride 40 shorts (80 B)
    __shared__ unsigned short Bs[64 * 40];
    __shared__ float red_s[4][64];
    __shared__ float red_d[4][64];
    int t = threadIdx.x;
    int w = t >> 6, l = t & 63;
    int quad = l >> 4, lm = l & 15;
    int m0 = blockIdx.y * 64, n0 = blockIdx.x * 64;
    int hd = blockIdx.x;
    int lr = t >> 2;            // staging row 0..63
    int lc = (t & 3) * 8;       // staging col offset 0/8/16/24

    f32x4 acc[4];
#pragma unroll
    for (int r = 0; r < 4; ++r) acc[r] = (f32x4){0.f, 0.f, 0.f, 0.f};

    for (int k0 = 0; k0 < K; k0 += 32) {
        int m = m0 + lr;
        if (AFP32) {
            float4 a0 = {0.f,0.f,0.f,0.f}, a1 = {0.f,0.f,0.f,0.f};
            if (m < M) {
                const float4* ap = (const float4*)(Af + (size_t)m * K + k0 + lc);
                a0 = ap[0]; a1 = ap[1];
            }
            unsigned int u0 = (unsigned int)f2b(a0.x) | ((unsigned int)f2b(a0.y) << 16);
            unsigned int u1 = (unsigned int)f2b(a0.z) | ((unsigned int)f2b(a0.w) << 16);
            unsigned int u2 = (unsigned int)f2b(a1.x) | ((unsigned int)f2b(a1.y) << 16);
            unsigned int u3 = (unsigned int)f2b(a1.z) | ((unsigned int)f2b(a1.w) << 16);
            *(uint4*)&As[lr * 40 + lc] = make_uint4(u0, u1, u2, u3);
        } else {
            uint4 av = make_uint4(0, 0, 0, 0);
            if (m < M) av = *(const uint4*)(Ab + (size_t)m * K + k0 + lc);
            *(uint4*)&As[lr * 40 + lc] = av;
        }
        uint4 bv = *(const uint4*)(W + (size_t)(n0 + lr) * K + k0 + lc);
        *(uint4*)&Bs[lr * 40 + lc] = bv;
        __syncthreads();

        bf16x8 bfrag = *(const bf16x8*)&Bs[(w * 16 + lm) * 40 + quad * 8];
#pragma unroll
        for (int r = 0; r < 4; ++r) {
            bf16x8 afrag = *(const bf16x8*)&As[(r * 16 + lm) * 40 + quad * 8];
            acc[r] = __builtin_amdgcn_mfma_f32_16x16x32_bf16(afrag, bfrag, acc[r], 0, 0, 0);
        }
        __syncthreads();
    }

    // C store (bf16)
#pragma unroll
    for (int r = 0; r < 4; ++r)
#pragma unroll
        for (int g = 0; g < 4; ++g) {
            int m = m0 + r * 16 + quad * 4 + g;
            if (m < M) C[(size_t)m * Nout + n0 + w * 16 + lm] = f2b(acc[r][g]);
        }

    // Attention-coefficient epilogue (fp32 accumulators)
    float as = a_src[hd * 64 + w * 16 + lm];
    float ad = a_dst[hd * 64 + w * 16 + lm];
#pragma unroll
    for (int r = 0; r < 4; ++r) {
#pragma unroll
        for (int g = 0; g < 4; ++g) {
            float vs = acc[r][g] * as;
            float vd = acc[r][g] * ad;
#pragma unroll
            for (int off = 1; off < 16; off <<= 1) {
                vs += __shfl_xor(vs, off);
                vd += __shfl_xor(vd, off);
            }
            if (lm == 0) {
                red_s[w][r * 16 + quad * 4 + g] = vs;
                red_d[w][r * 16 + quad * 4 + g] = vd;
            }
        }
    }
    __syncthreads();
    if (t < 64) {
        float vs = red_s[0][t] + red_s[1][t] + red_s[2][t] + red_s[3][t];
        float vd = red_d[0][t] + red_d[1][t] + red_d[2][t] + red_d[3][t];
        int m = m0 + t;
        if (m < M) {
            asb[(size_t)m * Hstr + hd] = vs;
            adb[(size_t)m * Hstr + hd] = vd;
        }
    }
}

// ---------------------------------------------------------------------------
// Fused segment-softmax + aggregation, H=8, C=64 (layer 1), bf16 h.
// v3: 2-deep software pipeline over padded 4-edge groups. Gathers for group
// g+1 are issued before accumulating group g (~8KB in flight per wave); col
// indices prefetched a full group ahead; pad slots predicated to weight 0.
// ---------------------------------------------------------------------------
__global__ __launch_bounds__(256) void k_agg8(const unsigned short* __restrict__ h, // [N,512]
                                              const float* __restrict__ asrc,       // [N,8]
                                              const float* __restrict__ adst,       // [N,8]
                                              const int* __restrict__ rowptr,       // padded starts
                                              const int* __restrict__ degv,
                                              const int* __restrict__ col,
                                              const float* __restrict__ bias,       // [512]
                                              unsigned short* __restrict__ out) {   // [N,512]
    int n = blockIdx.x * 4 + (threadIdx.x >> 6);
    if (n >= N_NODES) return;
    int l = threadIdx.x & 63;
    int j = l >> 3;
    unsigned lbase = (unsigned)(l << 3);
    int start = rowptr[n];
    int end   = start + degv[n];
    float adn = adst[((unsigned)n << 3) + (unsigned)j];

    float ssum = 0.f;
    f32x2 o2[4];
#pragma unroll
    for (int i = 0; i < 4; ++i) o2[i] = (f32x2){0.f, 0.f};

    float tA0, tA1, tA2, tA3, tB0, tB1, tB2, tB3;
    uint4 hA0, hA1, hA2, hA3, hB0, hB1, hB2, hB3;
    int4 cA, cB;

// t loads issued first (exp chain can start while 1KB h-gathers in flight)
#define GATH8(c, T0, T1, T2, T3, H0, H1, H2, H3)                              \
    T0 = asrc[(((unsigned)(c).x) << 3) + (unsigned)j];                        \
    T1 = asrc[(((unsigned)(c).y) << 3) + (unsigned)j];                        \
    T2 = asrc[(((unsigned)(c).z) << 3) + (unsigned)j];                        \
    T3 = asrc[(((unsigned)(c).w) << 3) + (unsigned)j];                        \
    H0 = *(const uint4*)(h + (((unsigned)(c).x) << 9) + lbase);               \
    H1 = *(const uint4*)(h + (((unsigned)(c).y) << 9) + lbase);               \
    H2 = *(const uint4*)(h + (((unsigned)(c).z) << 9) + lbase);               \
    H3 = *(const uint4*)(h + (((unsigned)(c).w) << 9) + lbase);

#define ASLOT8(IDX, TT, HH, rem)                                              \
    {                                                                         \
        float e = TT + adn;                                                   \
        e = fmaxf(e, 0.2f * e);                                               \
        float ex = __expf(e);                                                 \
        ex = ((IDX) < (rem)) ? ex : 0.f;                                      \
        ssum += ex;                                                           \
        f32x2 ex2 = {ex, ex};                                                 \
        f32x2 f;                                                              \
        f.x = __uint_as_float((HH).x << 16);                                  \
        f.y = __uint_as_float((HH).x & 0xffff0000u);                          \
        asm("v_pk_fma_f32 %0, %1, %2, %0" : "+v"(o2[0]) : "v"(f), "v"(ex2));  \
        f.x = __uint_as_float((HH).y << 16);                                  \
        f.y = __uint_as_float((HH).y & 0xffff0000u);                          \
        asm("v_pk_fma_f32 %0, %1, %2, %0" : "+v"(o2[1]) : "v"(f), "v"(ex2));  \
        f.x = __uint_as_float((HH).z << 16);                                  \
        f.y = __uint_as_float((HH).z & 0xffff0000u);                          \
        asm("v_pk_fma_f32 %0, %1, %2, %0" : "+v"(o2[2]) : "v"(f), "v"(ex2));  \
        f.x = __uint_as_float((HH).w << 16);                                  \
        f.y = __uint_as_float((HH).w & 0xffff0000u);                          \
        asm("v_pk_fma_f32 %0, %1, %2, %0" : "+v"(o2[3]) : "v"(f), "v"(ex2));  \
    }

    int k = start;
    cA = *(const int4*)(col + k);
    cB = *(const int4*)(col + k + 4);
    GATH8(cA, tA0, tA1, tA2, tA3, hA0, hA1, hA2, hA3);
    for (;;) {
        bool hasB = (k + 4 < end);
        if (hasB) {
            GATH8(cB, tB0, tB1, tB2, tB3, hB0, hB1, hB2, hB3);
            cA = *(const int4*)(col + k + 8);
        }
        {
            int rem = end - k;
            ASLOT8(0, tA0, hA0, rem);
            ASLOT8(1, tA1, hA1, rem);
            ASLOT8(2, tA2, hA2, rem);
            ASLOT8(3, tA3, hA3, rem);
        }
        k += 4;
        if (!hasB) break;
        bool hasA = (k + 4 < end);
        if (hasA) {
            GATH8(cA, tA0, tA1, tA2, tA3, hA0, hA1, hA2, hA3);
            cB = *(const int4*)(col + k + 8);
        }
        {
            int rem = end - k;
            ASLOT8(0, tB0, hB0, rem);
            ASLOT8(1, tB1, hB1, rem);
            ASLOT8(2, tB2, hB2, rem);
            ASLOT8(3, tB3, hB3, rem);
        }
        k += 4;
        if (!hasA) break;
    }
#undef GATH8
#undef ASLOT8

    float inv = 1.f / (ssum + 1e-16f);
    unsigned int p[4];
#pragma unroll
    for (int i = 0; i < 4; ++i) {
        float v0 = o2[i].x * inv + bias[lbase + 2 * i];
        float v1 = o2[i].y * inv + bias[lbase + 2 * i + 1];
        v0 = (v0 > 0.f) ? v0 : expm1f(v0);
        v1 = (v1 > 0.f) ? v1 : expm1f(v1);
        p[i] = (unsigned int)f2b(v0) | ((unsigned int)f2b(v1) << 16);
    }
    *(uint4*)(out + (size_t)n * 512 + lbase) = make_uint4(p[0], p[1], p[2], p[3]);
}

// ---------------------------------------------------------------------------
// Fused segment-softmax + aggregation, H=1, C=64 (layers 2,3), bf16 h.
// v3: same 2-deep pipeline over padded 4-edge groups.
// ---------------------------------------------------------------------------
__global__ __launch_bounds__(256) void k_agg1(const unsigned short* __restrict__ h, // [N,64]
                                              const float* __restrict__ asrc,       // [N]
                                              const float* __restrict__ adst,       // [N]
                                              const int* __restrict__ rowptr,       // padded starts
                                              const int* __restrict__ degv,
                                              const int* __restrict__ col,
                                              const float* __restrict__ bias,       // [64]
                                              unsigned short* __restrict__ out) {   // [N,64]
    int n = blockIdx.x * 4 + (threadIdx.x >> 6);
    if (n >= N_NODES) return;
    int l = threadIdx.x & 63;
    int start = rowptr[n];
    int end   = start + degv[n];
    float adn = adst[n];

    float ssum = 0.f, o = 0.f;
    float tA0, tA1, tA2, tA3, tB0, tB1, tB2, tB3;
    unsigned short qA0, qA1, qA2, qA3, qB0, qB1, qB2, qB3;
    int4 cA, cB;

#define GATH1(c, T0, T1, T2, T3, Q0, Q1, Q2, Q3)                              \
    T0 = asrc[(unsigned)(c).x];                                               \
    T1 = asrc[(unsigned)(c).y];                                               \
    T2 = asrc[(unsigned)(c).z];                                               \
    T3 = asrc[(unsigned)(c).w];                                               \
    Q0 = h[(((unsigned)(c).x) << 6) + (unsigned)l];                           \
    Q1 = h[(((unsigned)(c).y) << 6) + (unsigned)l];                           \
    Q2 = h[(((unsigned)(c).z) << 6) + (unsigned)l];                           \
    Q3 = h[(((unsigned)(c).w) << 6) + (unsigned)l];

#define ASLOT1(IDX, TT, QQ, rem)                                              \
    {                                                                         \
        float e = TT + adn;                                                   \
        e = fmaxf(e, 0.2f * e);                                               \
        float ex = __expf(e);                                                 \
        ex = ((IDX) < (rem)) ? ex : 0.f;                                      \
        ssum += ex;                                                           \
        o += ex * b2f(QQ);                                                    \
    }

    int k = start;
    cA = *(const int4*)(col + k);
    cB = *(const int4*)(col + k + 4);
    GATH1(cA, tA0, tA1, tA2, tA3, qA0, qA1, qA2, qA3);
    for (;;) {
        bool hasB = (k + 4 < end);
        if (hasB) {
            GATH1(cB, tB0, tB1, tB2, tB3, qB0, qB1, qB2, qB3);
            cA = *(const int4*)(col + k + 8);
        }
        {
            int rem = end - k;
            ASLOT1(0, tA0, qA0, rem);
            ASLOT1(1, tA1, qA1, rem);
            ASLOT1(2, tA2, qA2, rem);
            ASLOT1(3, tA3, qA3, rem);
        }
        k += 4;
        if (!hasB) break;
        bool hasA = (k + 4 < end);
        if (hasA) {
            GATH1(cA, tA0, tA1, tA2, tA3, qA0, qA1, qA2, qA3);
            cB = *(const int4*)(col + k + 8);
        }
        {
            int rem = end - k;
            ASLOT1(0, tB0, qB0, rem);
            ASLOT1(1, tB1, qB1, rem);
            ASLOT1(2, tB2, qB2, rem);
            ASLOT1(3, tB3, qB3, rem);
        }
        k += 4;
        if (!hasA) break;
    }
#undef GATH1
#undef ASLOT1

    float v = o / (ssum + 1e-16f) + bias[l];
    v = (v > 0.f) ? v : expm1f(v);   // ELU
    out[(size_t)n * 64 + l] = f2b(v);
}

// ---------------------------------------------------------------------------
// Classifier: out[N,10] = h[N,64](bf16) @ Wc[10,64]^T + bc, fp32 out.
// ---------------------------------------------------------------------------
__global__ __launch_bounds__(256) void k_classifier(const unsigned short* __restrict__ h,
                                                    const float* __restrict__ Wc,
                                                    const float* __restrict__ bc,
                                                    float* __restrict__ out) {
    __shared__ float sW[640];
    for (int i = threadIdx.x; i < 640; i += blockDim.x) sW[i] = Wc[i];
    __syncthreads();
    int idx = blockIdx.x * blockDim.x + threadIdx.x;
    if (idx >= N_NODES * 10) return;
    int n = idx / 10, d = idx - n * 10;
    const unsigned short* hr = h + (size_t)n * 64;
    const float* wr = sW + d * 64;
    float acc = 0.f;
#pragma unroll
    for (int c = 0; c < 64; ++c) acc += b2f(hr[c]) * wr[c];
    out[idx] = acc + bc[d];
}

// ---------------------------------------------------------------------------
extern "C" void kernel_launch(void* const* d_in, const int* in_sizes, int n_in,
                              void* d_out, int out_size, void* d_ws, size_t ws_size,
                              hipStream_t stream) {
    const float* x    = (const float*)d_in[0];
    const int*   eidx = (const int*)  d_in[1];
    const float* W1   = (const float*)d_in[2];
    const float* a1s  = (const float*)d_in[3];
    const float* a1d  = (const float*)d_in[4];
    const float* b1   = (const float*)d_in[5];
    const float* W2   = (const float*)d_in[6];
    const float* a2s  = (const float*)d_in[7];
    const float* a2d  = (const float*)d_in[8];
    const float* b2   = (const float*)d_in[9];
    const float* W3   = (const float*)d_in[10];
    const float* a3s  = (const float*)d_in[11];
    const float* a3d  = (const float*)d_in[12];
    const float* b3   = (const float*)d_in[13];
    const float* Wc   = (const float*)d_in[14];
    const float* bc   = (const float*)d_in[15];
    float* out = (float*)d_out;

    // Workspace layout: fp32 first (16B alignment), then bf16, then ints
    float* asbuf = (float*)d_ws;                              // N*8
    float* adbuf = asbuf + (size_t)N_NODES * 8;               // N*8
    unsigned short* h1  = (unsigned short*)(adbuf + (size_t)N_NODES * 8); // N*512
    unsigned short* x2  = h1  + (size_t)N_NODES * 512;        // N*512
    unsigned short* h2  = x2  + (size_t)N_NODES * 512;        // N*64
    unsigned short* x3  = h2  + (size_t)N_NODES * 64;         // N*64
    unsigned short* h3  = x3  + (size_t)N_NODES * 64;         // N*64
    unsigned short* x4  = h3  + (size_t)N_NODES * 64;         // N*64
    unsigned short* xb  = x4  + (size_t)N_NODES * 64;         // N*128 (bf16 x)
    unsigned short* W1b = xb  + (size_t)N_NODES * 128;        // 512*128
    unsigned short* W2b = W1b + 512 * 128;                    // 64*512
    unsigned short* W3b = W2b + 64 * 512;                     // 64*64
    int* ibase  = (int*)(W3b + 64 * 64);
    int* deg    = ibase;                                      // N   (zeroed in k_prep)
    int* flag   = deg + N_NODES;                              // 1   (zeroed in k_prep)
    int* rowptr = flag + 1;                                   // N+1 (padded starts)
    int* cursor = rowptr + N_NODES + 1;                       // N
    int* bsum   = cursor + N_NODES;                           // 256
    int* boff   = bsum + 256;                                 // 256
    int* col    = boff + 256;                                 // COL_CAP

    dim3 blk(256);
    const int SCAN_BLOCKS = (N_NODES + 255) / 256;            // 196
    const int PREP_BLOCKS = (N_NODES * 128 / 8 + 255) / 256;  // 3125

    // Prep (zero deg/flag + weight & x casts), then CSR build
    k_prep<<<PREP_BLOCKS, blk, 0, stream>>>(x, W1, W2, W3, xb, W1b, W2b, W3b, deg, flag);
    k_detect<<<32, blk, 0, stream>>>(eidx, flag);
    k_degree<<<(ETOT + 255) / 256, blk, 0, stream>>>(eidx, flag, deg);
    k_scan1<<<SCAN_BLOCKS, blk, 0, stream>>>(deg, rowptr, bsum);
    k_scan2<<<1, blk, 0, stream>>>(bsum, boff, rowptr, SCAN_BLOCKS);
    k_scan3<<<SCAN_BLOCKS, blk, 0, stream>>>(rowptr, boff, deg, cursor, col);
    k_scatter<<<(ETOT + 255) / 256, blk, 0, stream>>>(eidx, flag, cursor, col);

    int mblocks = (N_NODES + 63) / 64;   // 782
    int nblocks = N_NODES / 4;           // 12500 (exact)

    // Layer 1: xb[N,128] bf16 -> h1[N,512] (+ attn coefs); agg -> x2
    k_gemm<0><<<dim3(8, mblocks), blk, 0, stream>>>((const float*)0, xb, W1b, h1,
                                                    a1s, a1d, asbuf, adbuf,
                                                    N_NODES, 128, 512, 8);
    k_agg8<<<nblocks, blk, 0, stream>>>(h1, asbuf, adbuf, rowptr, deg, col, b1, x2);

    // Layer 2: x2[N,512] -> h2[N,64] (+ attn coefs); agg -> x3
    k_gemm<0><<<dim3(1, mblocks), blk, 0, stream>>>((const float*)0, x2, W2b, h2,
                                                    a2s, a2d, asbuf, adbuf,
                                                    N_NODES, 512, 64, 1);
    k_agg1<<<nblocks, blk, 0, stream>>>(h2, asbuf, adbuf, rowptr, deg, col, b2, x3);

    // Layer 3: x3[N,64] -> h3[N,64] (+ attn coefs); agg -> x4
    k_gemm<0><<<dim3(1, mblocks), blk, 0, stream>>>((const float*)0, x3, W3b, h3,
                                                    a3s, a3d, asbuf, adbuf,
                                                    N_NODES, 64, 64, 1);
    k_agg1<<<nblocks, blk, 0, stream>>>(h3, asbuf, adbuf, rowptr, deg, col, b3, x4);

    // Classifier
    k_classifier<<<(N_NODES * 10 + 255) / 256, blk, 0, stream>>>(x4, Wc, bc, out);
}

// Round 3
// 436.695 us; speedup vs baseline: 1.1741x; 1.1524x over previous
//
#include <hip/hip_runtime.h>
#include <math.h>

#define N_NODES 50000
#define N_EDGES 800000
#define ETOT    (N_EDGES + N_NODES)   // 850000, with self loops
// col array: padded rows (each row padded to multiple of 4) + 16-int tail
#define COL_CAP (ETOT + 3 * N_NODES + 16)

typedef short bf16x8 __attribute__((ext_vector_type(8)));
typedef float f32x4  __attribute__((ext_vector_type(4)));
typedef float f32x2  __attribute__((ext_vector_type(2)));

__device__ __forceinline__ float b2f(unsigned int u16) {   // low 16 bits hold bf16
    return __uint_as_float(u16 << 16);
}
__device__ __forceinline__ unsigned short f2b(float f) {   // RNE
    unsigned int u = __float_as_uint(f);
    u += 0x7fffu + ((u >> 16) & 1u);
    return (unsigned short)(u >> 16);
}

// ---------------------------------------------------------------------------
// Prep: zero deg+flag, cast W1/W2/W3 fp32->bf16, cast x fp32->bf16.
// ---------------------------------------------------------------------------
__global__ __launch_bounds__(256) void k_prep(const float* __restrict__ x,
                                              const float* __restrict__ w1,
                                              const float* __restrict__ w2,
                                              const float* __restrict__ w3,
                                              unsigned short* __restrict__ xb,
                                              unsigned short* __restrict__ o1,
                                              unsigned short* __restrict__ o2,
                                              unsigned short* __restrict__ o3,
                                              int* __restrict__ deg,
                                              int* __restrict__ flag) {
    int i = blockIdx.x * 256 + threadIdx.x;
    if (i < N_NODES) deg[i] = 0;
    if (i == 0) *flag = 0;
    if (i < 512 * 128 / 4) {
        float4 v = ((const float4*)w1)[i];
        ushort2* o = (ushort2*)(o1 + i * 4);
        o[0] = make_ushort2(f2b(v.x), f2b(v.y));
        o[1] = make_ushort2(f2b(v.z), f2b(v.w));
    }
    if (i < 64 * 512 / 4) {
        float4 v = ((const float4*)w2)[i];
        ushort2* o = (ushort2*)(o2 + i * 4);
        o[0] = make_ushort2(f2b(v.x), f2b(v.y));
        o[1] = make_ushort2(f2b(v.z), f2b(v.w));
    }
    if (i < 64 * 64 / 4) {
        float4 v = ((const float4*)w3)[i];
        ushort2* o = (ushort2*)(o3 + i * 4);
        o[0] = make_ushort2(f2b(v.x), f2b(v.y));
        o[1] = make_ushort2(f2b(v.z), f2b(v.w));
    }
    if (i < N_NODES * 128 / 8) {
        const float4* xp = (const float4*)x + (size_t)i * 2;
        float4 v0 = xp[0], v1 = xp[1];
        unsigned int u0 = (unsigned int)f2b(v0.x) | ((unsigned int)f2b(v0.y) << 16);
        unsigned int u1 = (unsigned int)f2b(v0.z) | ((unsigned int)f2b(v0.w) << 16);
        unsigned int u2 = (unsigned int)f2b(v1.x) | ((unsigned int)f2b(v1.y) << 16);
        unsigned int u3 = (unsigned int)f2b(v1.z) | ((unsigned int)f2b(v1.w) << 16);
        *(uint4*)(xb + (size_t)i * 8) = make_uint4(u0, u1, u2, u3);
    }
}

// ---------------------------------------------------------------------------
// U[16][128]: rows 0..7 = W1_h^T a1_src_h, rows 8..15 = W1_h^T a1_dst_h (fp32)
// asrc[n,h] = xb[n] . U[h], adst[n,h] = xb[n] . U[8+h]
// ---------------------------------------------------------------------------
__global__ __launch_bounds__(256) void k_prepu(const float* __restrict__ W1,
                                               const float* __restrict__ a1s,
                                               const float* __restrict__ a1d,
                                               float* __restrict__ U) {
    int h = blockIdx.x;          // 0..7
    int t = threadIdx.x;
    int which = t >> 7, k = t & 127;
    const float* av = which ? a1d : a1s;
    float acc = 0.f;
    for (int c = 0; c < 64; ++c)
        acc += av[h * 64 + c] * W1[(size_t)(h * 64 + c) * 128 + k];
    U[(which * 8 + h) * 128 + k] = acc;
}

// ---------------------------------------------------------------------------
// Attention logits from input space: asrc/adst[N,8] = xb[N,128] . U
// 16 nodes per block; U and xb rows staged in LDS (padded strides).
// ---------------------------------------------------------------------------
__global__ __launch_bounds__(256) void k_attn(const unsigned short* __restrict__ xb,
                                              const float* __restrict__ U,
                                              float* __restrict__ asrc,
                                              float* __restrict__ adst) {
    __shared__ float sU[16 * 132];           // stride 132 floats
    __shared__ unsigned short sX[16 * 136];  // stride 136 shorts (16B-aligned rows)
    int t = threadIdx.x;
    for (int i = t; i < 2048; i += 256) sU[(i >> 7) * 132 + (i & 127)] = U[i];
    int n0 = blockIdx.x * 16;
    {
        int r = t >> 4, c = (t & 15) * 8;
        *(uint4*)&sX[r * 136 + c] = *(const uint4*)(xb + (size_t)(n0 + r) * 128 + c);
    }
    __syncthreads();
    int nl = t >> 4, o = t & 15;
    const unsigned short* xr = sX + nl * 136;
    const float* ur = sU + o * 132;
    float acc = 0.f;
#pragma unroll 8
    for (int k2 = 0; k2 < 128; ++k2) acc += b2f(xr[k2]) * ur[k2];
    int n = n0 + nl;
    if (o < 8) asrc[n * 8 + o] = acc;
    else       adst[n * 8 + (o - 8)] = acc;
}

// ---------------------------------------------------------------------------
// Edge-index dtype detection (reference int64 vs harness int32).
// ---------------------------------------------------------------------------
__global__ void k_detect(const int* __restrict__ idx, int* __restrict__ flag) {
    int i = blockIdx.x * blockDim.x + threadIdx.x;   // 8192 threads
    int v = idx[2 * i + 1];
    unsigned long long any = __ballot(v != 0);
    if ((threadIdx.x & 63) == 0 && any) atomicOr(flag, 1);   // 1 => int32 data
}

__device__ __forceinline__ int edge_src(const int* idx, int e, int is32) {
    return is32 ? idx[e] : idx[2 * e];
}
__device__ __forceinline__ int edge_dst(const int* idx, int e, int is32) {
    return is32 ? idx[N_EDGES + e] : idx[2 * (N_EDGES + e)];
}

// ---------------------------------------------------------------------------
// CSR build: degree -> 3-kernel scan (PADDED row starts) -> scatter
// ---------------------------------------------------------------------------
__global__ void k_degree(const int* __restrict__ idx, const int* __restrict__ flag,
                         int* __restrict__ deg) {
    int e = blockIdx.x * blockDim.x + threadIdx.x;
    if (e >= ETOT) return;
    int is32 = *flag;
    int d = (e < N_EDGES) ? edge_dst(idx, e, is32) : (e - N_EDGES);
    atomicAdd(&deg[d], 1);
}

__global__ __launch_bounds__(256) void k_scan1(const int* __restrict__ deg,
                                               int* __restrict__ rowptr,
                                               int* __restrict__ bsum) {
    __shared__ int sd[256];
    int t = threadIdx.x;
    int i = blockIdx.x * 256 + t;
    int v = (i < N_NODES) ? ((deg[i] + 3) & ~3) : 0;   // padded degree
    sd[t] = v;
    __syncthreads();
#pragma unroll
    for (int off = 1; off < 256; off <<= 1) {
        int a = (t >= off) ? sd[t - off] : 0;
        __syncthreads();
        sd[t] += a;
        __syncthreads();
    }
    if (i < N_NODES) rowptr[i] = sd[t] - v;
    if (t == 255) bsum[blockIdx.x] = sd[255];
}

__global__ __launch_bounds__(256) void k_scan2(int* __restrict__ bsum,
                                               int* __restrict__ boff,
                                               int* __restrict__ rowptr,
                                               int nb) {
    __shared__ int sd[256];
    int t = threadIdx.x;
    int v = (t < nb) ? bsum[t] : 0;
    sd[t] = v;
    __syncthreads();
#pragma unroll
    for (int off = 1; off < 256; off <<= 1) {
        int a = (t >= off) ? sd[t - off] : 0;
        __syncthreads();
        sd[t] += a;
        __syncthreads();
    }
    boff[t] = sd[t] - v;
    if (t == 255) rowptr[N_NODES] = sd[255];    // total padded length
}

__global__ __launch_bounds__(256) void k_scan3(int* __restrict__ rowptr,
                                               const int* __restrict__ boff,
                                               const int* __restrict__ deg,
                                               int* __restrict__ cursor,
                                               int* __restrict__ col) {
    int i = blockIdx.x * 256 + threadIdx.x;
    if (i == 0) {                                // zero 16-int tail pad
        int tot = rowptr[N_NODES];
        for (int q = 0; q < 16; ++q) col[tot + q] = 0;
    }
    if (i >= N_NODES) return;
    int r = rowptr[i] + boff[blockIdx.x];
    rowptr[i] = r;
    cursor[i] = r;
    int d = deg[i];
    int pd = (d + 3) & ~3;
    for (int p = r + d; p < r + pd; ++p) col[p] = 0;   // zero row pads
}

__global__ void k_scatter(const int* __restrict__ idx, const int* __restrict__ flag,
                          int* __restrict__ cursor, int* __restrict__ col) {
    int e = blockIdx.x * blockDim.x + threadIdx.x;
    if (e >= ETOT) return;
    int is32 = *flag;
    int s, d;
    if (e < N_EDGES) { s = edge_src(idx, e, is32); d = edge_dst(idx, e, is32); }
    else             { s = d = e - N_EDGES; }
    int pos = atomicAdd(&cursor[d], 1);
    col[pos] = s;
}

// ---------------------------------------------------------------------------
// bf16 MFMA GEMM: C[M,*] = A[M,K] @ W[Nout-block,K]^T, A row stride Astr,
// A column offset blockIdx.x*aoffmul. 64x64 tile, 4 waves.
// EPI=0: bf16 C store + attention-coefficient epilogue (layers 2,3).
// EPI=1: fused bias+ELU bf16 store only (layer-1 post-aggregation GEMM).
// ---------------------------------------------------------------------------
template<int EPI>
__global__ __launch_bounds__(256) void k_gemm(const unsigned short* __restrict__ Ab,
                                              const unsigned short* __restrict__ W,
                                              unsigned short* __restrict__ C,
                                              const float* __restrict__ a_src,
                                              const float* __restrict__ a_dst,
                                              float* __restrict__ asb,
                                              float* __restrict__ adb,
                                              const float* __restrict__ bias,
                                              int M, int K, int Astr, int aoffmul,
                                              int Nout, int Hstr) {
    __shared__ unsigned short As[64 * 40];   // row stride 40 shorts (80 B)
    __shared__ unsigned short Bs[64 * 40];
    __shared__ float red_s[4][64];
    __shared__ float red_d[4][64];
    int t = threadIdx.x;
    int w = t >> 6, l = t & 63;
    int quad = l >> 4, lm = l & 15;
    int m0 = blockIdx.y * 64, n0 = blockIdx.x * 64;
    int hd = blockIdx.x;
    int aoff = hd * aoffmul;
    int lr = t >> 2;            // staging row 0..63
    int lc = (t & 3) * 8;       // staging col offset 0/8/16/24

    f32x4 acc[4];
#pragma unroll
    for (int r = 0; r < 4; ++r) acc[r] = (f32x4){0.f, 0.f, 0.f, 0.f};

    for (int k0 = 0; k0 < K; k0 += 32) {
        int m = m0 + lr;
        uint4 av = make_uint4(0, 0, 0, 0);
        if (m < M) av = *(const uint4*)(Ab + (size_t)m * Astr + aoff + k0 + lc);
        *(uint4*)&As[lr * 40 + lc] = av;
        uint4 bv = *(const uint4*)(W + (size_t)(n0 + lr) * K + k0 + lc);
        *(uint4*)&Bs[lr * 40 + lc] = bv;
        __syncthreads();

        bf16x8 bfrag = *(const bf16x8*)&Bs[(w * 16 + lm) * 40 + quad * 8];
#pragma unroll
        for (int r = 0; r < 4; ++r) {
            bf16x8 afrag = *(const bf16x8*)&As[(r * 16 + lm) * 40 + quad * 8];
            acc[r] = __builtin_amdgcn_mfma_f32_16x16x32_bf16(afrag, bfrag, acc[r], 0, 0, 0);
        }
        __syncthreads();
    }

    if (EPI == 1) {
        float bcol = bias[n0 + w * 16 + lm];
#pragma unroll
        for (int r = 0; r < 4; ++r)
#pragma unroll
            for (int g = 0; g < 4; ++g) {
                int m = m0 + r * 16 + quad * 4 + g;
                if (m < M) {
                    float v = acc[r][g] + bcol;
                    v = (v > 0.f) ? v : expm1f(v);
                    C[(size_t)m * Nout + n0 + w * 16 + lm] = f2b(v);
                }
            }
        return;
    }

    // C store (bf16)
#pragma unroll
    for (int r = 0; r < 4; ++r)
#pragma unroll
        for (int g = 0; g < 4; ++g) {
            int m = m0 + r * 16 + quad * 4 + g;
            if (m < M) C[(size_t)m * Nout + n0 + w * 16 + lm] = f2b(acc[r][g]);
        }

    // Attention-coefficient epilogue (fp32 accumulators)
    float as = a_src[hd * 64 + w * 16 + lm];
    float ad = a_dst[hd * 64 + w * 16 + lm];
#pragma unroll
    for (int r = 0; r < 4; ++r) {
#pragma unroll
        for (int g = 0; g < 4; ++g) {
            float vs = acc[r][g] * as;
            float vd = acc[r][g] * ad;
#pragma unroll
            for (int off = 1; off < 16; off <<= 1) {
                vs += __shfl_xor(vs, off);
                vd += __shfl_xor(vd, off);
            }
            if (lm == 0) {
                red_s[w][r * 16 + quad * 4 + g] = vs;
                red_d[w][r * 16 + quad * 4 + g] = vd;
            }
        }
    }
    __syncthreads();
    if (t < 64) {
        float vs = red_s[0][t] + red_s[1][t] + red_s[2][t] + red_s[3][t];
        float vd = red_d[0][t] + red_d[1][t] + red_d[2][t] + red_d[3][t];
        int m = m0 + t;
        if (m < M) {
            asb[(size_t)m * Hstr + hd] = vs;
            adb[(size_t)m * Hstr + hd] = vd;
        }
    }
}

// ---------------------------------------------------------------------------
// Layer-1 aggregation in INPUT space (256B/edge gather instead of 1KB).
// aggX[n, h*128 + c] = (Sum_e w_h(e) xb[src_e, c]) / Sum_e w_h(e), bf16.
// Wave per node; lane l holds channels {2l,2l+1} for all 8 heads (16 fp32 acc).
// One exp per wave per edge (lane group j = l>>3 computes head j's weight);
// per-head broadcast via readlane. Padded 4-edge groups, 2-deep pipeline.
// ---------------------------------------------------------------------------
__device__ __forceinline__ void aggx_slot(int idx, int rem, float tt, unsigned int xx,
                                          float adn, float& ssum, f32x2* acc) {
    float e = tt + adn;
    e = fmaxf(e, 0.2f * e);
    float ex = __expf(e);
    ex = (idx < rem) ? ex : 0.f;
    ssum += ex;
    float fx = __uint_as_float(xx << 16);
    float fy = __uint_as_float(xx & 0xffff0000u);
    int exi = __float_as_int(ex);
#pragma unroll
    for (int hh = 0; hh < 8; ++hh) {
        float wh = __int_as_float(__builtin_amdgcn_readlane(exi, hh << 3));
        acc[hh].x = fmaf(fx, wh, acc[hh].x);
        acc[hh].y = fmaf(fy, wh, acc[hh].y);
    }
}

__global__ __launch_bounds__(256) void k_aggx(const unsigned short* __restrict__ xb,  // [N,128]
                                              const float* __restrict__ asrc,         // [N,8]
                                              const float* __restrict__ adst,         // [N,8]
                                              const int* __restrict__ rowptr,         // padded starts
                                              const int* __restrict__ degv,
                                              const int* __restrict__ col,
                                              unsigned short* __restrict__ aggX) {    // [N,1024]
    int n = blockIdx.x * 4 + (threadIdx.x >> 6);
    if (n >= N_NODES) return;
    int l = threadIdx.x & 63;
    int j = l >> 3;
    unsigned lx2 = (unsigned)(l << 1);
    int start = rowptr[n];
    int end   = start + degv[n];
    float adn = adst[((unsigned)n << 3) + (unsigned)j];

    float ssum = 0.f;
    f32x2 acc[8];
#pragma unroll
    for (int hh = 0; hh < 8; ++hh) acc[hh] = (f32x2){0.f, 0.f};

    float tA0, tA1, tA2, tA3, tB0, tB1, tB2, tB3;
    unsigned int xA0, xA1, xA2, xA3, xB0, xB1, xB2, xB3;
    int4 cA, cB;

#define GATHX(c, T0, T1, T2, T3, X0, X1, X2, X3)                              \
    T0 = asrc[(((unsigned)(c).x) << 3) + (unsigned)j];                        \
    T1 = asrc[(((unsigned)(c).y) << 3) + (unsigned)j];                        \
    T2 = asrc[(((unsigned)(c).z) << 3) + (unsigned)j];                        \
    T3 = asrc[(((unsigned)(c).w) << 3) + (unsigned)j];                        \
    X0 = *(const unsigned int*)(xb + (((unsigned)(c).x) << 7) + lx2);         \
    X1 = *(const unsigned int*)(xb + (((unsigned)(c).y) << 7) + lx2);         \
    X2 = *(const unsigned int*)(xb + (((unsigned)(c).z) << 7) + lx2);         \
    X3 = *(const unsigned int*)(xb + (((unsigned)(c).w) << 7) + lx2);

    int k = start;
    cA = *(const int4*)(col + k);
    cB = *(const int4*)(col + k + 4);
    GATHX(cA, tA0, tA1, tA2, tA3, xA0, xA1, xA2, xA3);
    for (;;) {
        bool hasB = (k + 4 < end);
        if (hasB) {
            GATHX(cB, tB0, tB1, tB2, tB3, xB0, xB1, xB2, xB3);
            cA = *(const int4*)(col + k + 8);
        }
        {
            int rem = end - k;
            aggx_slot(0, rem, tA0, xA0, adn, ssum, acc);
            aggx_slot(1, rem, tA1, xA1, adn, ssum, acc);
            aggx_slot(2, rem, tA2, xA2, adn, ssum, acc);
            aggx_slot(3, rem, tA3, xA3, adn, ssum, acc);
        }
        k += 4;
        if (!hasB) break;
        bool hasA = (k + 4 < end);
        if (hasA) {
            GATHX(cA, tA0, tA1, tA2, tA3, xA0, xA1, xA2, xA3);
            cB = *(const int4*)(col + k + 8);
        }
        {
            int rem = end - k;
            aggx_slot(0, rem, tB0, xB0, adn, ssum, acc);
            aggx_slot(1, rem, tB1, xB1, adn, ssum, acc);
            aggx_slot(2, rem, tB2, xB2, adn, ssum, acc);
            aggx_slot(3, rem, tB3, xB3, adn, ssum, acc);
        }
        k += 4;
        if (!hasA) break;
    }
#undef GATHX

    // normalize and store: per head, wave writes 256B contiguous
    size_t base = (size_t)n * 1024 + lx2;
#pragma unroll
    for (int hh = 0; hh < 8; ++hh) {
        float sh = __int_as_float(__builtin_amdgcn_readlane(__float_as_int(ssum), hh << 3));
        float iv = 1.f / (sh + 1e-16f);
        unsigned int lo = f2b(acc[hh].x * iv);
        unsigned int hi = f2b(acc[hh].y * iv);
        *(unsigned int*)(aggX + base + hh * 128) = lo | (hi << 16);
    }
}

// ---------------------------------------------------------------------------
// Fused segment-softmax + aggregation, H=1, C=64 (layers 2,3), bf16 h.
// 2-deep pipeline over padded 4-edge groups.
// ---------------------------------------------------------------------------
__global__ __launch_bounds__(256) void k_agg1(const unsigned short* __restrict__ h, // [N,64]
                                              const float* __restrict__ asrc,       // [N]
                                              const float* __restrict__ adst,       // [N]
                                              const int* __restrict__ rowptr,       // padded starts
                                              const int* __restrict__ degv,
                                              const int* __restrict__ col,
                                              const float* __restrict__ bias,       // [64]
                                              unsigned short* __restrict__ out) {   // [N,64]
    int n = blockIdx.x * 4 + (threadIdx.x >> 6);
    if (n >= N_NODES) return;
    int l = threadIdx.x & 63;
    int start = rowptr[n];
    int end   = start + degv[n];
    float adn = adst[n];

    float ssum = 0.f, o = 0.f;
    float tA0, tA1, tA2, tA3, tB0, tB1, tB2, tB3;
    unsigned short qA0, qA1, qA2, qA3, qB0, qB1, qB2, qB3;
    int4 cA, cB;

#define GATH1(c, T0, T1, T2, T3, Q0, Q1, Q2, Q3)                              \
    T0 = asrc[(unsigned)(c).x];                                               \
    T1 = asrc[(unsigned)(c).y];                                               \
    T2 = asrc[(unsigned)(c).z];                                               \
    T3 = asrc[(unsigned)(c).w];                                               \
    Q0 = h[(((unsigned)(c).x) << 6) + (unsigned)l];                           \
    Q1 = h[(((unsigned)(c).y) << 6) + (unsigned)l];                           \
    Q2 = h[(((unsigned)(c).z) << 6) + (unsigned)l];                           \
    Q3 = h[(((unsigned)(c).w) << 6) + (unsigned)l];

#define ASLOT1(IDX, TT, QQ, rem)                                              \
    {                                                                         \
        float e = TT + adn;                                                   \
        e = fmaxf(e, 0.2f * e);                                               \
        float ex = __expf(e);                                                 \
        ex = ((IDX) < (rem)) ? ex : 0.f;                                      \
        ssum += ex;                                                           \
        o += ex * b2f(QQ);                                                    \
    }

    int k = start;
    cA = *(const int4*)(col + k);
    cB = *(const int4*)(col + k + 4);
    GATH1(cA, tA0, tA1, tA2, tA3, qA0, qA1, qA2, qA3);
    for (;;) {
        bool hasB = (k + 4 < end);
        if (hasB) {
            GATH1(cB, tB0, tB1, tB2, tB3, qB0, qB1, qB2, qB3);
            cA = *(const int4*)(col + k + 8);
        }
        {
            int rem = end - k;
            ASLOT1(0, tA0, qA0, rem);
            ASLOT1(1, tA1, qA1, rem);
            ASLOT1(2, tA2, qA2, rem);
            ASLOT1(3, tA3, qA3, rem);
        }
        k += 4;
        if (!hasB) break;
        bool hasA = (k + 4 < end);
        if (hasA) {
            GATH1(cA, tA0, tA1, tA2, tA3, qA0, qA1, qA2, qA3);
            cB = *(const int4*)(col + k + 8);
        }
        {
            int rem = end - k;
            ASLOT1(0, tB0, qB0, rem);
            ASLOT1(1, tB1, qB1, rem);
            ASLOT1(2, tB2, qB2, rem);
            ASLOT1(3, tB3, qB3, rem);
        }
        k += 4;
        if (!hasA) break;
    }
#undef GATH1
#undef ASLOT1

    float v = o / (ssum + 1e-16f) + bias[l];
    v = (v > 0.f) ? v : expm1f(v);   // ELU
    out[(size_t)n * 64 + l] = f2b(v);
}

// ---------------------------------------------------------------------------
// Classifier: out[N,10] = h[N,64](bf16) @ Wc[10,64]^T + bc, fp32 out.
// ---------------------------------------------------------------------------
__global__ __launch_bounds__(256) void k_classifier(const unsigned short* __restrict__ h,
                                                    const float* __restrict__ Wc,
                                                    const float* __restrict__ bc,
                                                    float* __restrict__ out) {
    __shared__ float sW[640];
    for (int i = threadIdx.x; i < 640; i += blockDim.x) sW[i] = Wc[i];
    __syncthreads();
    int idx = blockIdx.x * blockDim.x + threadIdx.x;
    if (idx >= N_NODES * 10) return;
    int n = idx / 10, d = idx - n * 10;
    const unsigned short* hr = h + (size_t)n * 64;
    const float* wr = sW + d * 64;
    float acc = 0.f;
#pragma unroll
    for (int c = 0; c < 64; ++c) acc += b2f(hr[c]) * wr[c];
    out[idx] = acc + bc[d];
}

// ---------------------------------------------------------------------------
extern "C" void kernel_launch(void* const* d_in, const int* in_sizes, int n_in,
                              void* d_out, int out_size, void* d_ws, size_t ws_size,
                              hipStream_t stream) {
    const float* x    = (const float*)d_in[0];
    const int*   eidx = (const int*)  d_in[1];
    const float* W1   = (const float*)d_in[2];
    const float* a1s  = (const float*)d_in[3];
    const float* a1d  = (const float*)d_in[4];
    const float* b1   = (const float*)d_in[5];
    const float* W2   = (const float*)d_in[6];
    const float* a2s  = (const float*)d_in[7];
    const float* a2d  = (const float*)d_in[8];
    const float* b2   = (const float*)d_in[9];
    const float* W3   = (const float*)d_in[10];
    const float* a3s  = (const float*)d_in[11];
    const float* a3d  = (const float*)d_in[12];
    const float* b3   = (const float*)d_in[13];
    const float* Wc   = (const float*)d_in[14];
    const float* bc   = (const float*)d_in[15];
    float* out = (float*)d_out;

    // Workspace layout
    float* asbuf = (float*)d_ws;                              // N*8 fp32
    float* adbuf = asbuf + (size_t)N_NODES * 8;               // N*8 fp32
    unsigned short* aggX = (unsigned short*)(adbuf + (size_t)N_NODES * 8); // N*1024
    unsigned short* x2  = aggX + (size_t)N_NODES * 1024;      // N*512
    unsigned short* xb  = x2  + (size_t)N_NODES * 512;        // N*128 (bf16 x)
    unsigned short* W1b = xb  + (size_t)N_NODES * 128;        // 512*128
    unsigned short* W2b = W1b + 512 * 128;                    // 64*512
    unsigned short* W3b = W2b + 64 * 512;                     // 64*64
    float* U    = (float*)(W3b + 64 * 64);                    // 16*128 fp32
    int* ibase  = (int*)(U + 16 * 128);
    int* deg    = ibase;                                      // N (zeroed in k_prep)
    int* flag   = deg + N_NODES;                              // 1
    int* rowptr = flag + 1;                                   // N+1 (padded starts)
    int* cursor = rowptr + N_NODES + 1;                       // N
    int* bsum   = cursor + N_NODES;                           // 256
    int* boff   = bsum + 256;                                 // 256
    int* col    = boff + 256;                                 // COL_CAP
    // small per-layer buffers aliased into aggX (dead after layer-1 GEMM)
    unsigned short* h2 = aggX;                                // N*64
    unsigned short* x3 = h2 + (size_t)N_NODES * 64;           // N*64
    unsigned short* h3 = x3 + (size_t)N_NODES * 64;           // N*64
    unsigned short* x4 = h3 + (size_t)N_NODES * 64;           // N*64

    dim3 blk(256);
    const int SCAN_BLOCKS = (N_NODES + 255) / 256;            // 196
    const int PREP_BLOCKS = (N_NODES * 128 / 8 + 255) / 256;  // 3125

    // Prep: casts + U + attention logits (independent of CSR)
    k_prep<<<PREP_BLOCKS, blk, 0, stream>>>(x, W1, W2, W3, xb, W1b, W2b, W3b, deg, flag);
    k_prepu<<<8, blk, 0, stream>>>(W1, a1s, a1d, U);
    k_attn<<<N_NODES / 16, blk, 0, stream>>>(xb, U, asbuf, adbuf);

    // CSR build
    k_detect<<<32, blk, 0, stream>>>(eidx, flag);
    k_degree<<<(ETOT + 255) / 256, blk, 0, stream>>>(eidx, flag, deg);
    k_scan1<<<SCAN_BLOCKS, blk, 0, stream>>>(deg, rowptr, bsum);
    k_scan2<<<1, blk, 0, stream>>>(bsum, boff, rowptr, SCAN_BLOCKS);
    k_scan3<<<SCAN_BLOCKS, blk, 0, stream>>>(rowptr, boff, deg, cursor, col);
    k_scatter<<<(ETOT + 255) / 256, blk, 0, stream>>>(eidx, flag, cursor, col);

    int mblocks = (N_NODES + 63) / 64;   // 782
    int nblocks = N_NODES / 4;           // 12500 (exact)

    // Layer 1: aggregate xb in input space, then per-head GEMM with bias+ELU
    k_aggx<<<nblocks, blk, 0, stream>>>(xb, asbuf, adbuf, rowptr, deg, col, aggX);
    k_gemm<1><<<dim3(8, mblocks), blk, 0, stream>>>(aggX, W1b, x2,
                                                    (const float*)0, (const float*)0,
                                                    (float*)0, (float*)0, b1,
                                                    N_NODES, 128, 1024, 128, 512, 8);

    // Layer 2: x2[N,512] -> h2[N,64] (+ attn coefs); agg -> x3
    k_gemm<0><<<dim3(1, mblocks), blk, 0, stream>>>(x2, W2b, h2,
                                                    a2s, a2d, asbuf, adbuf, (const float*)0,
                                                    N_NODES, 512, 512, 0, 64, 1);
    k_agg1<<<nblocks, blk, 0, stream>>>(h2, asbuf, adbuf, rowptr, deg, col, b2, x3);

    // Layer 3: x3[N,64] -> h3[N,64] (+ attn coefs); agg -> x4
    k_gemm<0><<<dim3(1, mblocks), blk, 0, stream>>>(x3, W3b, h3,
                                                    a3s, a3d, asbuf, adbuf, (const float*)0,
                                                    N_NODES, 64, 64, 0, 64, 1);
    k_agg1<<<nblocks, blk, 0, stream>>>(h3, asbuf, adbuf, rowptr, deg, col, b3, x4);

    // Classifier
    k_classifier<<<(N_NODES * 10 + 255) / 256, blk, 0, stream>>>(x4, Wc, bc, out);
}

// Round 5
// 434.365 us; speedup vs baseline: 1.1804x; 1.0054x over previous
//
#include <hip/hip_runtime.h>
#include <math.h>

#define N_NODES 50000
#define N_EDGES 800000
#define ETOT    (N_EDGES + N_NODES)   // 850000, with self loops
// col array: padded rows (each row padded to multiple of 4) + 64-int tail
#define COL_CAP (ETOT + 3 * N_NODES + 64)

typedef short bf16x8 __attribute__((ext_vector_type(8)));
typedef float f32x4  __attribute__((ext_vector_type(4)));
typedef float f32x2  __attribute__((ext_vector_type(2)));

__device__ __forceinline__ float b2f(unsigned int u16) {   // low 16 bits hold bf16
    return __uint_as_float(u16 << 16);
}
__device__ __forceinline__ unsigned short f2b(float f) {   // RNE
    unsigned int u = __float_as_uint(f);
    u += 0x7fffu + ((u >> 16) & 1u);
    return (unsigned short)(u >> 16);
}

// ---------------------------------------------------------------------------
// Prep: zero deg+flag, cast W1/W2/W3 fp32->bf16, cast x fp32->bf16,
// and (blocks 0..7) build U[16][128]: rows 0..7 = W1_h^T a1_src_h,
// rows 8..15 = W1_h^T a1_dst_h (fp32).
// ---------------------------------------------------------------------------
__global__ __launch_bounds__(256) void k_prep(const float* __restrict__ x,
                                              const float* __restrict__ w1,
                                              const float* __restrict__ w2,
                                              const float* __restrict__ w3,
                                              const float* __restrict__ a1s,
                                              const float* __restrict__ a1d,
                                              unsigned short* __restrict__ xb,
                                              unsigned short* __restrict__ o1,
                                              unsigned short* __restrict__ o2,
                                              unsigned short* __restrict__ o3,
                                              float* __restrict__ U,
                                              int* __restrict__ deg,
                                              int* __restrict__ flag) {
    int i = blockIdx.x * 256 + threadIdx.x;
    if (i < N_NODES) deg[i] = 0;
    if (i == 0) *flag = 0;
    if (blockIdx.x < 8) {
        int h = blockIdx.x;
        int which = threadIdx.x >> 7, k = threadIdx.x & 127;
        const float* av = which ? a1d : a1s;
        float acc = 0.f;
        for (int c = 0; c < 64; ++c)
            acc += av[h * 64 + c] * w1[(size_t)(h * 64 + c) * 128 + k];
        U[(which * 8 + h) * 128 + k] = acc;
    }
    if (i < 512 * 128 / 4) {
        float4 v = ((const float4*)w1)[i];
        ushort2* o = (ushort2*)(o1 + i * 4);
        o[0] = make_ushort2(f2b(v.x), f2b(v.y));
        o[1] = make_ushort2(f2b(v.z), f2b(v.w));
    }
    if (i < 64 * 512 / 4) {
        float4 v = ((const float4*)w2)[i];
        ushort2* o = (ushort2*)(o2 + i * 4);
        o[0] = make_ushort2(f2b(v.x), f2b(v.y));
        o[1] = make_ushort2(f2b(v.z), f2b(v.w));
    }
    if (i < 64 * 64 / 4) {
        float4 v = ((const float4*)w3)[i];
        ushort2* o = (ushort2*)(o3 + i * 4);
        o[0] = make_ushort2(f2b(v.x), f2b(v.y));
        o[1] = make_ushort2(f2b(v.z), f2b(v.w));
    }
    if (i < N_NODES * 128 / 8) {
        const float4* xp = (const float4*)x + (size_t)i * 2;
        float4 v0 = xp[0], v1 = xp[1];
        unsigned int u0 = (unsigned int)f2b(v0.x) | ((unsigned int)f2b(v0.y) << 16);
        unsigned int u1 = (unsigned int)f2b(v0.z) | ((unsigned int)f2b(v0.w) << 16);
        unsigned int u2 = (unsigned int)f2b(v1.x) | ((unsigned int)f2b(v1.y) << 16);
        unsigned int u3 = (unsigned int)f2b(v1.z) | ((unsigned int)f2b(v1.w) << 16);
        *(uint4*)(xb + (size_t)i * 8) = make_uint4(u0, u1, u2, u3);
    }
}

// ---------------------------------------------------------------------------
// Attention logits from input space: asrc/adst[N,8] = xb[N,128] . U
// ---------------------------------------------------------------------------
__global__ __launch_bounds__(256) void k_attn(const unsigned short* __restrict__ xb,
                                              const float* __restrict__ U,
                                              float* __restrict__ asrc,
                                              float* __restrict__ adst) {
    __shared__ float sU[16 * 132];           // stride 132 floats
    __shared__ unsigned short sX[16 * 136];  // stride 136 shorts (16B-aligned rows)
    int t = threadIdx.x;
    for (int i = t; i < 2048; i += 256) sU[(i >> 7) * 132 + (i & 127)] = U[i];
    int n0 = blockIdx.x * 16;
    {
        int r = t >> 4, c = (t & 15) * 8;
        *(uint4*)&sX[r * 136 + c] = *(const uint4*)(xb + (size_t)(n0 + r) * 128 + c);
    }
    __syncthreads();
    int nl = t >> 4, o = t & 15;
    const unsigned short* xr = sX + nl * 136;
    const float* ur = sU + o * 132;
    float acc = 0.f;
#pragma unroll 8
    for (int k2 = 0; k2 < 128; ++k2) acc += b2f(xr[k2]) * ur[k2];
    int n = n0 + nl;
    if (o < 8) asrc[n * 8 + o] = acc;
    else       adst[n * 8 + (o - 8)] = acc;
}

// ---------------------------------------------------------------------------
// Edge-index dtype detection (reference int64 vs harness int32).
// ---------------------------------------------------------------------------
__global__ void k_detect(const int* __restrict__ idx, int* __restrict__ flag) {
    int i = blockIdx.x * blockDim.x + threadIdx.x;   // 8192 threads
    int v = idx[2 * i + 1];
    unsigned long long any = __ballot(v != 0);
    if ((threadIdx.x & 63) == 0 && any) atomicOr(flag, 1);   // 1 => int32 data
}

__device__ __forceinline__ int edge_src(const int* idx, int e, int is32) {
    return is32 ? idx[e] : idx[2 * e];
}
__device__ __forceinline__ int edge_dst(const int* idx, int e, int is32) {
    return is32 ? idx[N_EDGES + e] : idx[2 * (N_EDGES + e)];
}

// ---------------------------------------------------------------------------
// CSR build: degree -> 3-kernel scan (PADDED row starts) -> scatter
// ---------------------------------------------------------------------------
__global__ void k_degree(const int* __restrict__ idx, const int* __restrict__ flag,
                         int* __restrict__ deg) {
    int e = blockIdx.x * blockDim.x + threadIdx.x;
    if (e >= ETOT) return;
    int is32 = *flag;
    int d = (e < N_EDGES) ? edge_dst(idx, e, is32) : (e - N_EDGES);
    atomicAdd(&deg[d], 1);
}

__global__ __launch_bounds__(256) void k_scan1(const int* __restrict__ deg,
                                               int* __restrict__ rowptr,
                                               int* __restrict__ bsum) {
    __shared__ int sd[256];
    int t = threadIdx.x;
    int i = blockIdx.x * 256 + t;
    int v = (i < N_NODES) ? ((deg[i] + 3) & ~3) : 0;   // padded degree
    sd[t] = v;
    __syncthreads();
#pragma unroll
    for (int off = 1; off < 256; off <<= 1) {
        int a = (t >= off) ? sd[t - off] : 0;
        __syncthreads();
        sd[t] += a;
        __syncthreads();
    }
    if (i < N_NODES) rowptr[i] = sd[t] - v;
    if (t == 255) bsum[blockIdx.x] = sd[255];
}

__global__ __launch_bounds__(256) void k_scan2(int* __restrict__ bsum,
                                               int* __restrict__ boff,
                                               int* __restrict__ rowptr,
                                               int nb) {
    __shared__ int sd[256];
    int t = threadIdx.x;
    int v = (t < nb) ? bsum[t] : 0;
    sd[t] = v;
    __syncthreads();
#pragma unroll
    for (int off = 1; off < 256; off <<= 1) {
        int a = (t >= off) ? sd[t - off] : 0;
        __syncthreads();
        sd[t] += a;
        __syncthreads();
    }
    boff[t] = sd[t] - v;
    if (t == 255) rowptr[N_NODES] = sd[255];    // total padded length
}

__global__ __launch_bounds__(256) void k_scan3(int* __restrict__ rowptr,
                                               const int* __restrict__ boff,
                                               const int* __restrict__ deg,
                                               int* __restrict__ cursor,
                                               int* __restrict__ col) {
    int i = blockIdx.x * 256 + threadIdx.x;
    if (i == 0) {                                // zero 48-int tail pad
        int tot = rowptr[N_NODES];
        for (int q = 0; q < 48; ++q) col[tot + q] = 0;
    }
    if (i >= N_NODES) return;
    int r = rowptr[i] + boff[blockIdx.x];
    rowptr[i] = r;
    cursor[i] = r;
    int d = deg[i];
    int pd = (d + 3) & ~3;
    for (int p = r + d; p < r + pd; ++p) col[p] = 0;   // zero row pads
}

__global__ void k_scatter(const int* __restrict__ idx, const int* __restrict__ flag,
                          int* __restrict__ cursor, int* __restrict__ col) {
    int e = blockIdx.x * blockDim.x + threadIdx.x;
    if (e >= ETOT) return;
    int is32 = *flag;
    int s, d;
    if (e < N_EDGES) { s = edge_src(idx, e, is32); d = edge_dst(idx, e, is32); }
    else             { s = d = e - N_EDGES; }
    int pos = atomicAdd(&cursor[d], 1);
    col[pos] = s;
}

// ---------------------------------------------------------------------------
// bf16 MFMA GEMM: C[M,*] = A[M,K] @ W[Nout-block,K]^T, A row stride Astr,
// A column offset blockIdx.x*aoffmul. 64x64 tile, 4 waves.
// EPI=0: bf16 C store + attention-coefficient epilogue (layers 2,3).
// EPI=1: fused bias+ELU bf16 store only (layer-1 post-aggregation GEMM).
// ---------------------------------------------------------------------------
template<int EPI>
__global__ __launch_bounds__(256) void k_gemm(const unsigned short* __restrict__ Ab,
                                              const unsigned short* __restrict__ W,
                                              unsigned short* __restrict__ C,
                                              const float* __restrict__ a_src,
                                              const float* __restrict__ a_dst,
                                              float* __restrict__ asb,
                                              float* __restrict__ adb,
                                              const float* __restrict__ bias,
                                              int M, int K, int Astr, int aoffmul,
                                              int Nout, int Hstr) {
    __shared__ unsigned short As[64 * 40];   // row stride 40 shorts (80 B)
    __shared__ unsigned short Bs[64 * 40];
    __shared__ float red_s[4][64];
    __shared__ float red_d[4][64];
    int t = threadIdx.x;
    int w = t >> 6, l = t & 63;
    int quad = l >> 4, lm = l & 15;
    int m0 = blockIdx.y * 64, n0 = blockIdx.x * 64;
    int hd = blockIdx.x;
    int aoff = hd * aoffmul;
    int lr = t >> 2;            // staging row 0..63
    int lc = (t & 3) * 8;       // staging col offset 0/8/16/24

    f32x4 acc[4];
#pragma unroll
    for (int r = 0; r < 4; ++r) acc[r] = (f32x4){0.f, 0.f, 0.f, 0.f};

    for (int k0 = 0; k0 < K; k0 += 32) {
        int m = m0 + lr;
        uint4 av = make_uint4(0, 0, 0, 0);
        if (m < M) av = *(const uint4*)(Ab + (size_t)m * Astr + aoff + k0 + lc);
        *(uint4*)&As[lr * 40 + lc] = av;
        uint4 bv = *(const uint4*)(W + (size_t)(n0 + lr) * K + k0 + lc);
        *(uint4*)&Bs[lr * 40 + lc] = bv;
        __syncthreads();

        bf16x8 bfrag = *(const bf16x8*)&Bs[(w * 16 + lm) * 40 + quad * 8];
#pragma unroll
        for (int r = 0; r < 4; ++r) {
            bf16x8 afrag = *(const bf16x8*)&As[(r * 16 + lm) * 40 + quad * 8];
            acc[r] = __builtin_amdgcn_mfma_f32_16x16x32_bf16(afrag, bfrag, acc[r], 0, 0, 0);
        }
        __syncthreads();
    }

    if (EPI == 1) {
        float bcol = bias[n0 + w * 16 + lm];
#pragma unroll
        for (int r = 0; r < 4; ++r)
#pragma unroll
            for (int g = 0; g < 4; ++g) {
                int m = m0 + r * 16 + quad * 4 + g;
                if (m < M) {
                    float v = acc[r][g] + bcol;
                    v = (v > 0.f) ? v : expm1f(v);
                    C[(size_t)m * Nout + n0 + w * 16 + lm] = f2b(v);
                }
            }
        return;
    }

    // C store (bf16)
#pragma unroll
    for (int r = 0; r < 4; ++r)
#pragma unroll
        for (int g = 0; g < 4; ++g) {
            int m = m0 + r * 16 + quad * 4 + g;
            if (m < M) C[(size_t)m * Nout + n0 + w * 16 + lm] = f2b(acc[r][g]);
        }

    // Attention-coefficient epilogue (fp32 accumulators)
    float as = a_src[hd * 64 + w * 16 + lm];
    float ad = a_dst[hd * 64 + w * 16 + lm];
#pragma unroll
    for (int r = 0; r < 4; ++r) {
#pragma unroll
        for (int g = 0; g < 4; ++g) {
            float vs = acc[r][g] * as;
            float vd = acc[r][g] * ad;
#pragma unroll
            for (int off = 1; off < 16; off <<= 1) {
                vs += __shfl_xor(vs, off);
                vd += __shfl_xor(vd, off);
            }
            if (lm == 0) {
                red_s[w][r * 16 + quad * 4 + g] = vs;
                red_d[w][r * 16 + quad * 4 + g] = vd;
            }
        }
    }
    __syncthreads();
    if (t < 64) {
        float vs = red_s[0][t] + red_s[1][t] + red_s[2][t] + red_s[3][t];
        float vd = red_d[0][t] + red_d[1][t] + red_d[2][t] + red_d[3][t];
        int m = m0 + t;
        if (m < M) {
            asb[(size_t)m * Hstr + hd] = vs;
            adb[(size_t)m * Hstr + hd] = vd;
        }
    }
}

// ---------------------------------------------------------------------------
// Layer-1 aggregation via MFMA. Wave per node, 32-edge chunks.
// C[ch][head] = Sum_k X[ch][k] * W[head][k] with X staged transposed in LDS
// ([128][34] bf16) and W (exp attention weights) computed in-register in
// B-fragment layout (lane: head=lm, k=8q+j). bf16 weight + bf16 residual ->
// 2 MFMAs per tile keep weight precision at fp32 level. Slots >= deg get
// weight 0. Output aggX[n][head*128+ch] = C[ch][head] / ssum[head], bf16.
//
// LDS hazard note: the staging writes (short lvalues) and fragment reads
// (uint lvalues) are TBAA-distinct, and there is NO __syncthreads here
// (wave-private region, divergent chunk counts). The inline-asm fences
// below are REQUIRED: without them the compiler may hoist the reads above
// the writes / skip the lgkmcnt wait (R4 failed with NaN exactly so).
// ---------------------------------------------------------------------------
__global__ __launch_bounds__(256) void k_aggx(const unsigned short* __restrict__ xb,  // [N,128]
                                              const float* __restrict__ asrc,         // [N,8]
                                              const float* __restrict__ adst,         // [N,8]
                                              const int* __restrict__ rowptr,         // padded starts
                                              const int* __restrict__ degv,
                                              const int* __restrict__ col,
                                              unsigned short* __restrict__ aggX) {    // [N,1024]
    __shared__ unsigned short sX[4][128 * 34];
    int wid = threadIdx.x >> 6;
    int n = blockIdx.x * 4 + wid;
    if (n >= N_NODES) return;
    int l = threadIdx.x & 63;
    int lm = l & 15, q = l >> 4;
    unsigned short* sx = sX[wid];

    int start = rowptr[n];
    int deg   = degv[n];
    float adn = adst[((unsigned)n << 3) + (unsigned)(lm & 7)];

    f32x4 acc[8];
#pragma unroll
    for (int i = 0; i < 8; ++i) acc[i] = (f32x4){0.f, 0.f, 0.f, 0.f};
    float ssum = 0.f;
    unsigned ls = (unsigned)(l << 1);

    int nch = (deg + 31) >> 5;
    for (int ch = 0; ch < nch; ++ch) {
        int base = start + (ch << 5);
        const int4* cp = (const int4*)(col + base);

        // keep this chunk's LDS writes ordered after previous chunk's reads
        asm volatile("" ::: "memory");

        // ---- stage 32 gathered rows, transposed, 2 batches of 16 ----
#define XLD(S) (*(const unsigned int*)(xb + (((unsigned)(S)) << 7) + ls))
#define XST(E, D) { sx[(2 * l) * 34 + (E)] = (unsigned short)((D) & 0xffffu);       \
                    sx[(2 * l + 1) * 34 + (E)] = (unsigned short)((D) >> 16); }
        {
            int4 c0 = cp[0], c1 = cp[1], c2 = cp[2], c3 = cp[3];
            unsigned int d0 = XLD(c0.x), d1 = XLD(c0.y), d2 = XLD(c0.z), d3 = XLD(c0.w);
            unsigned int d4 = XLD(c1.x), d5 = XLD(c1.y), d6 = XLD(c1.z), d7 = XLD(c1.w);
            unsigned int d8 = XLD(c2.x), d9 = XLD(c2.y), dA = XLD(c2.z), dB = XLD(c2.w);
            unsigned int dC = XLD(c3.x), dD = XLD(c3.y), dE = XLD(c3.z), dF = XLD(c3.w);
            XST(0, d0)  XST(1, d1)  XST(2, d2)  XST(3, d3)
            XST(4, d4)  XST(5, d5)  XST(6, d6)  XST(7, d7)
            XST(8, d8)  XST(9, d9)  XST(10, dA) XST(11, dB)
            XST(12, dC) XST(13, dD) XST(14, dE) XST(15, dF)
        }
        {
            int4 c4 = cp[4], c5 = cp[5], c6 = cp[6], c7 = cp[7];
            unsigned int d0 = XLD(c4.x), d1 = XLD(c4.y), d2 = XLD(c4.z), d3 = XLD(c4.w);
            unsigned int d4 = XLD(c5.x), d5 = XLD(c5.y), d6 = XLD(c5.z), d7 = XLD(c5.w);
            unsigned int d8 = XLD(c6.x), d9 = XLD(c6.y), dA = XLD(c6.z), dB = XLD(c6.w);
            unsigned int dC = XLD(c7.x), dD = XLD(c7.y), dE = XLD(c7.z), dF = XLD(c7.w);
            XST(16, d0) XST(17, d1) XST(18, d2) XST(19, d3)
            XST(20, d4) XST(21, d5) XST(22, d6) XST(23, d7)
            XST(24, d8) XST(25, d9) XST(26, dA) XST(27, dB)
            XST(28, dC) XST(29, dD) XST(30, dE) XST(31, dF)
        }
#undef XLD
#undef XST

        // ---- per-lane B-fragment weights: head lm, slots 8q+j ----
        int slot0 = (ch << 5) + (q << 3);
        float wv[8];
#pragma unroll
        for (int j = 0; j < 8; ++j) {
            int s = col[base + (q << 3) + j];
            float tt = asrc[((unsigned)s << 3) + (unsigned)lm];   // lm>=8 strays into adbuf: safe, zeroed below
            float e = tt + adn;
            e = fmaxf(e, 0.2f * e);
            float ex = __expf(e);
            bool valid = (lm < 8) && (slot0 + j < deg);
            ex = valid ? ex : 0.f;
            ssum += ex;
            wv[j] = ex;
        }
        unsigned int wp[4], rp[4];
#pragma unroll
        for (int p = 0; p < 4; ++p) {
            unsigned int h0 = f2b(wv[2 * p]), h1 = f2b(wv[2 * p + 1]);
            wp[p] = h0 | (h1 << 16);
            float r0 = wv[2 * p]     - b2f(h0);
            float r1 = wv[2 * p + 1] - b2f(h1);
            rp[p] = (unsigned int)f2b(r0) | ((unsigned int)f2b(r1) << 16);
        }
        uint4 wpu = make_uint4(wp[0], wp[1], wp[2], wp[3]);
        uint4 rpu = make_uint4(rp[0], rp[1], rp[2], rp[3]);
        bf16x8 wf_hi = *(bf16x8*)&wpu;
        bf16x8 wf_lo = *(bf16x8*)&rpu;

        // drain LDS writes and pin the fragment reads after them (rule #18)
        asm volatile("s_waitcnt lgkmcnt(0)" ::: "memory");
        __builtin_amdgcn_sched_barrier(0);

        // ---- 8 tiles x 2 MFMAs ----
#pragma unroll
        for (int ct = 0; ct < 8; ++ct) {
            int row = ct * 16 + lm;
            const unsigned int* fp = (const unsigned int*)(sx + row * 34 + (q << 3));
            uint4 fu = make_uint4(fp[0], fp[1], fp[2], fp[3]);
            bf16x8 xf = *(bf16x8*)&fu;
            acc[ct] = __builtin_amdgcn_mfma_f32_16x16x32_bf16(xf, wf_hi, acc[ct], 0, 0, 0);
            acc[ct] = __builtin_amdgcn_mfma_f32_16x16x32_bf16(xf, wf_lo, acc[ct], 0, 0, 0);
        }
    }

    // ---- normalize + store (lanes lm<8 hold valid head columns) ----
    ssum += __shfl_xor(ssum, 16);
    ssum += __shfl_xor(ssum, 32);
    if (lm < 8) {
        float inv = 1.f / (ssum + 1e-16f);
        size_t obase = (size_t)n * 1024 + ((unsigned)lm << 7) + ((unsigned)q << 2);
#pragma unroll
        for (int ct = 0; ct < 8; ++ct) {
            unsigned int u0 = (unsigned int)f2b(acc[ct][0] * inv) |
                              ((unsigned int)f2b(acc[ct][1] * inv) << 16);
            unsigned int u1 = (unsigned int)f2b(acc[ct][2] * inv) |
                              ((unsigned int)f2b(acc[ct][3] * inv) << 16);
            *(uint2*)(aggX + obase + ct * 16) = make_uint2(u0, u1);
        }
    }
}

// ---------------------------------------------------------------------------
// Fused segment-softmax + aggregation, H=1, C=64 (layers 2,3), bf16 h.
// 2-deep pipeline over padded 4-edge groups.
// ---------------------------------------------------------------------------
__global__ __launch_bounds__(256) void k_agg1(const unsigned short* __restrict__ h, // [N,64]
                                              const float* __restrict__ asrc,       // [N]
                                              const float* __restrict__ adst,       // [N]
                                              const int* __restrict__ rowptr,       // padded starts
                                              const int* __restrict__ degv,
                                              const int* __restrict__ col,
                                              const float* __restrict__ bias,       // [64]
                                              unsigned short* __restrict__ out) {   // [N,64]
    int n = blockIdx.x * 4 + (threadIdx.x >> 6);
    if (n >= N_NODES) return;
    int l = threadIdx.x & 63;
    int start = rowptr[n];
    int end   = start + degv[n];
    float adn = adst[n];

    float ssum = 0.f, o = 0.f;
    float tA0, tA1, tA2, tA3, tB0, tB1, tB2, tB3;
    unsigned short qA0, qA1, qA2, qA3, qB0, qB1, qB2, qB3;
    int4 cA, cB;

#define GATH1(c, T0, T1, T2, T3, Q0, Q1, Q2, Q3)                              \
    T0 = asrc[(unsigned)(c).x];                                               \
    T1 = asrc[(unsigned)(c).y];                                               \
    T2 = asrc[(unsigned)(c).z];                                               \
    T3 = asrc[(unsigned)(c).w];                                               \
    Q0 = h[(((unsigned)(c).x) << 6) + (unsigned)l];                           \
    Q1 = h[(((unsigned)(c).y) << 6) + (unsigned)l];                           \
    Q2 = h[(((unsigned)(c).z) << 6) + (unsigned)l];                           \
    Q3 = h[(((unsigned)(c).w) << 6) + (unsigned)l];

#define ASLOT1(IDX, TT, QQ, rem)                                              \
    {                                                                         \
        float e = TT + adn;                                                   \
        e = fmaxf(e, 0.2f * e);                                               \
        float ex = __expf(e);                                                 \
        ex = ((IDX) < (rem)) ? ex : 0.f;                                      \
        ssum += ex;                                                           \
        o += ex * b2f(QQ);                                                    \
    }

    int k = start;
    cA = *(const int4*)(col + k);
    cB = *(const int4*)(col + k + 4);
    GATH1(cA, tA0, tA1, tA2, tA3, qA0, qA1, qA2, qA3);
    for (;;) {
        bool hasB = (k + 4 < end);
        if (hasB) {
            GATH1(cB, tB0, tB1, tB2, tB3, qB0, qB1, qB2, qB3);
            cA = *(const int4*)(col + k + 8);
        }
        {
            int rem = end - k;
            ASLOT1(0, tA0, qA0, rem);
            ASLOT1(1, tA1, qA1, rem);
            ASLOT1(2, tA2, qA2, rem);
            ASLOT1(3, tA3, qA3, rem);
        }
        k += 4;
        if (!hasB) break;
        bool hasA = (k + 4 < end);
        if (hasA) {
            GATH1(cA, tA0, tA1, tA2, tA3, qA0, qA1, qA2, qA3);
            cB = *(const int4*)(col + k + 8);
        }
        {
            int rem = end - k;
            ASLOT1(0, tB0, qB0, rem);
            ASLOT1(1, tB1, qB1, rem);
            ASLOT1(2, tB2, qB2, rem);
            ASLOT1(3, tB3, qB3, rem);
        }
        k += 4;
        if (!hasA) break;
    }
#undef GATH1
#undef ASLOT1

    float v = o / (ssum + 1e-16f) + bias[l];
    v = (v > 0.f) ? v : expm1f(v);   // ELU
    out[(size_t)n * 64 + l] = f2b(v);
}

// ---------------------------------------------------------------------------
// Classifier: out[N,10] = h[N,64](bf16) @ Wc[10,64]^T + bc, fp32 out.
// ---------------------------------------------------------------------------
__global__ __launch_bounds__(256) void k_classifier(const unsigned short* __restrict__ h,
                                                    const float* __restrict__ Wc,
                                                    const float* __restrict__ bc,
                                                    float* __restrict__ out) {
    __shared__ float sW[640];
    for (int i = threadIdx.x; i < 640; i += blockDim.x) sW[i] = Wc[i];
    __syncthreads();
    int idx = blockIdx.x * blockDim.x + threadIdx.x;
    if (idx >= N_NODES * 10) return;
    int n = idx / 10, d = idx - n * 10;
    const unsigned short* hr = h + (size_t)n * 64;
    const float* wr = sW + d * 64;
    float acc = 0.f;
#pragma unroll
    for (int c = 0; c < 64; ++c) acc += b2f(hr[c]) * wr[c];
    out[idx] = acc + bc[d];
}

// ---------------------------------------------------------------------------
extern "C" void kernel_launch(void* const* d_in, const int* in_sizes, int n_in,
                              void* d_out, int out_size, void* d_ws, size_t ws_size,
                              hipStream_t stream) {
    const float* x    = (const float*)d_in[0];
    const int*   eidx = (const int*)  d_in[1];
    const float* W1   = (const float*)d_in[2];
    const float* a1s  = (const float*)d_in[3];
    const float* a1d  = (const float*)d_in[4];
    const float* b1   = (const float*)d_in[5];
    const float* W2   = (const float*)d_in[6];
    const float* a2s  = (const float*)d_in[7];
    const float* a2d  = (const float*)d_in[8];
    const float* b2   = (const float*)d_in[9];
    const float* W3   = (const float*)d_in[10];
    const float* a3s  = (const float*)d_in[11];
    const float* a3d  = (const float*)d_in[12];
    const float* b3   = (const float*)d_in[13];
    const float* Wc   = (const float*)d_in[14];
    const float* bc   = (const float*)d_in[15];
    float* out = (float*)d_out;

    // Workspace layout
    float* asbuf = (float*)d_ws;                              // N*8 fp32
    float* adbuf = asbuf + (size_t)N_NODES * 8;               // N*8 fp32
    unsigned short* aggX = (unsigned short*)(adbuf + (size_t)N_NODES * 8); // N*1024
    unsigned short* x2  = aggX + (size_t)N_NODES * 1024;      // N*512
    unsigned short* xb  = x2  + (size_t)N_NODES * 512;        // N*128 (bf16 x)
    unsigned short* W1b = xb  + (size_t)N_NODES * 128;        // 512*128
    unsigned short* W2b = W1b + 512 * 128;                    // 64*512
    unsigned short* W3b = W2b + 64 * 512;                     // 64*64
    float* U    = (float*)(W3b + 64 * 64);                    // 16*128 fp32
    int* ibase  = (int*)(U + 16 * 128);
    int* deg    = ibase;                                      // N (zeroed in k_prep)
    int* flag   = deg + N_NODES;                              // 1
    int* rowptr = flag + 1;                                   // N+1 (padded starts)
    int* cursor = rowptr + N_NODES + 1;                       // N
    int* bsum   = cursor + N_NODES;                           // 256
    int* boff   = bsum + 256;                                 // 256
    int* col    = boff + 256;                                 // COL_CAP
    // small per-layer buffers aliased into aggX (dead after layer-1 GEMM)
    unsigned short* h2 = aggX;                                // N*64
    unsigned short* x3 = h2 + (size_t)N_NODES * 64;           // N*64
    unsigned short* h3 = x3 + (size_t)N_NODES * 64;           // N*64
    unsigned short* x4 = h3 + (size_t)N_NODES * 64;           // N*64

    dim3 blk(256);
    const int SCAN_BLOCKS = (N_NODES + 255) / 256;            // 196
    const int PREP_BLOCKS = (N_NODES * 128 / 8 + 255) / 256;  // 3125

    // Prep: casts + U + attention logits (independent of CSR)
    k_prep<<<PREP_BLOCKS, blk, 0, stream>>>(x, W1, W2, W3, a1s, a1d,
                                            xb, W1b, W2b, W3b, U, deg, flag);
    k_attn<<<N_NODES / 16, blk, 0, stream>>>(xb, U, asbuf, adbuf);

    // CSR build
    k_detect<<<32, blk, 0, stream>>>(eidx, flag);
    k_degree<<<(ETOT + 255) / 256, blk, 0, stream>>>(eidx, flag, deg);
    k_scan1<<<SCAN_BLOCKS, blk, 0, stream>>>(deg, rowptr, bsum);
    k_scan2<<<1, blk, 0, stream>>>(bsum, boff, rowptr, SCAN_BLOCKS);
    k_scan3<<<SCAN_BLOCKS, blk, 0, stream>>>(rowptr, boff, deg, cursor, col);
    k_scatter<<<(ETOT + 255) / 256, blk, 0, stream>>>(eidx, flag, cursor, col);

    int mblocks = (N_NODES + 63) / 64;   // 782
    int nblocks = N_NODES / 4;           // 12500 (exact)

    // Layer 1: MFMA aggregation of xb, then per-head GEMM with bias+ELU
    k_aggx<<<nblocks, blk, 0, stream>>>(xb, asbuf, adbuf, rowptr, deg, col, aggX);
    k_gemm<1><<<dim3(8, mblocks), blk, 0, stream>>>(aggX, W1b, x2,
                                                    (const float*)0, (const float*)0,
                                                    (float*)0, (float*)0, b1,
                                                    N_NODES, 128, 1024, 128, 512, 8);

    // Layer 2: x2[N,512] -> h2[N,64] (+ attn coefs); agg -> x3
    k_gemm<0><<<dim3(1, mblocks), blk, 0, stream>>>(x2, W2b, h2,
                                                    a2s, a2d, asbuf, adbuf, (const float*)0,
                                                    N_NODES, 512, 512, 0, 64, 1);
    k_agg1<<<nblocks, blk, 0, stream>>>(h2, asbuf, adbuf, rowptr, deg, col, b2, x3);

    // Layer 3: x3[N,64] -> h3[N,64] (+ attn coefs); agg -> x4
    k_gemm<0><<<dim3(1, mblocks), blk, 0, stream>>>(x3, W3b, h3,
                                                    a3s, a3d, asbuf, adbuf, (const float*)0,
                                                    N_NODES, 64, 64, 0, 64, 1);
    k_agg1<<<nblocks, blk, 0, stream>>>(h3, asbuf, adbuf, rowptr, deg, col, b3, x4);

    // Classifier
    k_classifier<<<(N_NODES * 10 + 255) / 256, blk, 0, stream>>>(x4, Wc, bc, out);
}